// Round 19
// baseline (89.690 us; speedup 1.0000x reference)
//
#include <hip/hip_runtime.h>
#include <math.h>

typedef _Float16 f16;
typedef _Float16 f16x2 __attribute__((ext_vector_type(2)));
typedef _Float16 f16x4 __attribute__((ext_vector_type(4)));
typedef _Float16 f16x8 __attribute__((ext_vector_type(8)));
typedef float f32x4 __attribute__((ext_vector_type(4)));

#if defined(__has_builtin)
#if __has_builtin(__builtin_amdgcn_fdot2)
#define USE_FDOT2 1
#endif
#if __has_builtin(__builtin_amdgcn_exp2f)
#define USE_EXP2 1
#endif
#endif

__device__ __forceinline__ float fdot2f(f16x2 a, f16x2 b, float c) {
#ifdef USE_FDOT2
    return __builtin_amdgcn_fdot2(a, b, c, false);
#else
    return c + (float)a.x * (float)b.x + (float)a.y * (float)b.y;
#endif
}
__device__ __forceinline__ float exp2fast(float a) {
#ifdef USE_EXP2
    return __builtin_amdgcn_exp2f(a);
#else
    return exp2f(a);
#endif
}

namespace {
// ---- k_att constants (r18: 2048 blocks, no staging; A-frags from g_h) ----
constexpr int KS  = 40;
constexpr int QLS = 40;
constexpr int VTS = 200;
constexpr int PSW = 40;
constexpr int OFF_KL = 0;            // 192*40*2 = 15360
constexpr int OFF_VT = 15360;        // 12800 -> 28160
constexpr int OFF_QL = 28160;        // 10240 -> 38400
constexpr int OFF_PW = 38400;        // 10240 -> 48640
constexpr int OFF_LI = 48640;        // f32[128] -> 49152
constexpr int OFF_PZ = 49152;        // f32[128] -> 49664
constexpr int ATT_LDS = 49664;       // x3 = 148992 < 160K -> 3 blocks/CU
constexpr float C1  = 0.2550600f;
constexpr float CZN = -5.7707801f;
constexpr float CZV = 2.5511480f;

// ---- packed-f16 weights: P[out][in/2] f16x2 pairs; row o = W[:,o] = B-fragment row o
constexpr int OFF_WQ  = 0;
constexpr int OFF_WKV = 4096;
constexpr int OFF_WO  = 12288;
constexpr int OFF_W1  = 16384;
constexpr int OFF_W2  = 20480;
constexpr int NPAIRS  = 24576;

// ---- k_epi constants (unchanged) ----
constexpr int EOLS = 136;
constexpr int ETVS = 66;
constexpr int EH2S = 72;
constexpr int OFF_EOL = 0;
constexpr int OFF_ETV = 17408;
constexpr int OFF_EH2 = 34304;
constexpr int OFF_ERD = 43520;
constexpr int EPI_LDS = 45568;
}

__device__ f16x2 g_wpack[NPAIRS];
__device__ f16 g_h[65536 * 64];      // LN1'd tokens, f16 (8.4 MB device global)

// ---------------- Kernel 0: pack GEMV weights to f16x2 ----------------
__global__ void k_conv(const float* __restrict__ Wq, const float* __restrict__ Wkv,
                       const float* __restrict__ Wo, const float* __restrict__ W1,
                       const float* __restrict__ W2) {
    const int i = blockIdx.x * 256 + threadIdx.x;
    const float* src; int inp, out, base;
    if (i < OFF_WKV)     { src = Wq;  inp = 32; out = 128; base = OFF_WQ;  }
    else if (i < OFF_WO) { src = Wkv; inp = 32; out = 256; base = OFF_WKV; }
    else if (i < OFF_W1) { src = Wo;  inp = 64; out = 64;  base = OFF_WO;  }
    else if (i < OFF_W2) { src = W1;  inp = 32; out = 128; base = OFF_W1;  }
    else                 { src = W2;  inp = 64; out = 64;  base = OFF_W2;  }
    const int li = i - base;
    const int o = li / inp, p = li % inp;
    g_wpack[i] = (f16x2){(f16)src[(2*p) * out + o], (f16)src[(2*p+1) * out + o]};
}

// ---------------- Kernel 0b: LN1 all 65536 tokens -> g_h (f16), once ----------------
// r18: the per-(window,head) blocks were each re-LN'ing shared rows; hoisted here.
__global__ __launch_bounds__(256, 2) void k_ln(
    const float* __restrict__ x,
    const float* __restrict__ ln1_s, const float* __restrict__ ln1_b) {
    __shared__ float xl[256 * 65];           // 66560 B, 65-stride: conflict-free
    const int tid = threadIdx.x;
    const size_t base = (size_t)blockIdx.x * 256 * 64;
    #pragma unroll
    for (int i = 0; i < 16; ++i) {
        const int li = i * 256 + tid;        // float4 index within block tile
        const float4 v = ((const float4*)(x + base))[li];
        float* d = xl + (li >> 4) * 65 + (li & 15) * 4;
        d[0] = v.x; d[1] = v.y; d[2] = v.z; d[3] = v.w;
    }
    __syncthreads();
    const float* xr = xl + tid * 65;
    float sm = 0.f, ss = 0.f;
    #pragma unroll
    for (int i = 0; i < 64; ++i) { const float a = xr[i]; sm += a; ss += a*a; }
    const float mean = sm * 0.015625f;
    const float rstd = rsqrtf(ss * 0.015625f - mean*mean + 1e-5f);
    f16* hr = g_h + ((size_t)blockIdx.x * 256 + tid) * 64;
    #pragma unroll
    for (int m = 0; m < 8; ++m) {
        f16x8 p;
        #pragma unroll
        for (int j = 0; j < 8; ++j)
            p[j] = (f16)((xr[m*8 + j] - mean) * rstd * ln1_s[m*8 + j] + ln1_b[m*8 + j]);
        ((f16x8*)hr)[m] = p;
    }
}

// ---------------- Kernel 1: per-(window,head) attention; A-frags from g_h ----------------
__global__ __launch_bounds__(256, 3) void k_att(
    const float* __restrict__ bkv,
    f16* __restrict__ o_out)
{
    __shared__ __align__(16) char smem[ATT_LDS];
    f16* kl   = (f16*)(smem + OFF_KL);
    f16* vt   = (f16*)(smem + OFF_VT);
    f16* ql   = (f16*)(smem + OFF_QL);
    float* linv = (float*)(smem + OFF_LI);
    float* pzn  = (float*)(smem + OFF_PZ);

    const int tid  = threadIdx.x;
    const int bid  = blockIdx.x;
    const int w    = bid & 511;
    const int head = bid >> 9;
    const int cb   = head * 32;
    const int n    = w & 255;
    const int t    = w >> 8;

    const int lane = tid & 63, wv = tid >> 6;
    const int lr = lane & 15, lg = lane >> 4;

    const f16* WqF  = (const f16*)(g_wpack + OFF_WQ);
    const f16* WkvF = (const f16*)(g_wpack + OFF_WKV);

    // Phase C: MFMA projections; A-fragments read directly from g_h
    // (each 16-row m-tile = 16 consecutive tokens of one (v,t2) segment).
    {
        #pragma unroll
        for (int mi = 0; mi < 3; ++mi) {
            const int seg = wv * 3 + mi;                    // 0..11
            const int v_ = seg / 6;
            const int t2 = (seg % 6) + ((t == 0) ? 2 : 0);
            int tsrc, tt;
            if (t2 < 2)      { tsrc = t - 1; tt = t2 + 2; }
            else if (t2 < 6) { tsrc = t;     tt = t2 - 2; }
            else             { tsrc = t + 1; tt = t2 - 6; }
            const size_t tb = (size_t)(v_ * 8 + tsrc * 4 + tt) * 4096 + n * 16;
            const int mb = seg * 16;
            #pragma unroll
            for (int nt = 0; nt < 2; ++nt) {
                f32x4 ck = {0.f,0.f,0.f,0.f}, cv = {0.f,0.f,0.f,0.f};
                #pragma unroll
                for (int ks = 0; ks < 2; ++ks) {
                    const f16x8 af = *(const f16x8*)(g_h + (tb + lr) * 64 + ks*32 + lg*8);
                    const f16x8 bk = *(const f16x8*)(WkvF + (cb + nt*16 + lr)*64 + ks*32 + lg*8);
                    const f16x8 bv = *(const f16x8*)(WkvF + (128 + cb + nt*16 + lr)*64 + ks*32 + lg*8);
                    ck = __builtin_amdgcn_mfma_f32_16x16x32_f16(af, bk, ck, 0, 0, 0);
                    cv = __builtin_amdgcn_mfma_f32_16x16x32_f16(af, bv, cv, 0, 0, 0);
                }
                const float bk_b = bkv[cb + nt*16 + lr];
                const float bv_b = bkv[128 + cb + nt*16 + lr];
                #pragma unroll
                for (int e = 0; e < 4; ++e) {
                    const int row = mb + lg*4 + e;
                    kl[row * KS + nt*16 + lr] = (f16)(ck[e] + bk_b);
                    vt[(nt*16 + lr) * VTS + row] = (f16)(cv[e] + bv_b);
                }
            }
        }
        #pragma unroll
        for (int mi = 0; mi < 2; ++mi) {
            const int qm = wv * 2 + mi;                     // 0..7
            const int v_ = qm >> 2, tt = qm & 3;
            const size_t tb = (size_t)(v_ * 8 + t * 4 + tt) * 4096 + n * 16;
            const int qb = v_ * 64 + tt * 16;
            #pragma unroll
            for (int nt = 0; nt < 2; ++nt) {
                f32x4 cq = {0.f,0.f,0.f,0.f};
                #pragma unroll
                for (int ks = 0; ks < 2; ++ks) {
                    const f16x8 af = *(const f16x8*)(g_h + (tb + lr) * 64 + ks*32 + lg*8);
                    const f16x8 bq = *(const f16x8*)(WqF + (cb + nt*16 + lr)*64 + ks*32 + lg*8);
                    cq = __builtin_amdgcn_mfma_f32_16x16x32_f16(af, bq, cq, 0, 0, 0);
                }
                #pragma unroll
                for (int e = 0; e < 4; ++e)
                    ql[(qb + lg*4 + e) * QLS + nt*16 + lr] = (f16)cq[e];
            }
        }
    }
    __syncthreads();

    const int mA = wv * 32;
    f16* Pw = (f16*)(smem + OFF_PW) + wv * 32 * PSW;
    const int prow = lane & 31, pcolh = lane >> 5;

    float pz = 0.f;
    if (tid < 128) {
        const f16x2* qr2 = (const f16x2*)(ql + tid * QLS);
        float sz = 0.f;
        #pragma unroll
        for (int j = 0; j < 16; ++j)
            sz += (float)qr2[j].x * bkv[cb + 2*j] + (float)qr2[j].y * bkv[cb + 2*j + 1];
        pz = exp2fast(fmaf(sz, C1, CZV));
    }

    f32x4 oc00 = {0.f,0.f,0.f,0.f}, oc01 = {0.f,0.f,0.f,0.f};
    f32x4 oc10 = {0.f,0.f,0.f,0.f}, oc11 = {0.f,0.f,0.f,0.f};
    float l_own = 0.f;

    #pragma unroll 1
    for (int kk = 0; kk < 6; ++kk) {
        #pragma unroll
        for (int mi = 0; mi < 2; ++mi) {
            const f16x8 af = *(const f16x8*)(ql + (mA + mi*16 + lr) * QLS + lg * 8);
            #pragma unroll
            for (int nt = 0; nt < 2; ++nt) {
                const f16x8 bf = *(const f16x8*)(kl + (kk*32 + nt*16 + lr) * KS + lg * 8);
                const f32x4 c = __builtin_amdgcn_mfma_f32_16x16x32_f16(af, bf, (f32x4){0.f,0.f,0.f,0.f}, 0, 0, 0);
                #pragma unroll
                for (int e = 0; e < 4; ++e)
                    Pw[(mi*16 + lg*4 + e) * PSW + nt*16 + lr] = (f16)exp2fast(fmaf(c[e], C1, CZN));
            }
        }
        const f16x8 a0 = *(const f16x8*)(Pw + lr * PSW + lg * 8);
        const f16x8 a1 = *(const f16x8*)(Pw + (16 + lr) * PSW + lg * 8);
        const f16x8 b0 = *(const f16x8*)(vt + lr * VTS + kk*32 + lg*8);
        const f16x8 b1 = *(const f16x8*)(vt + (16 + lr) * VTS + kk*32 + lg*8);
        oc00 = __builtin_amdgcn_mfma_f32_16x16x32_f16(a0, b0, oc00, 0, 0, 0);
        oc01 = __builtin_amdgcn_mfma_f32_16x16x32_f16(a0, b1, oc01, 0, 0, 0);
        oc10 = __builtin_amdgcn_mfma_f32_16x16x32_f16(a1, b0, oc10, 0, 0, 0);
        oc11 = __builtin_amdgcn_mfma_f32_16x16x32_f16(a1, b1, oc11, 0, 0, 0);
        {
            const f16x2* pr = (const f16x2*)(Pw + prow * PSW + pcolh * 16);
            const f16x2 ones = (f16x2){(f16)1.f, (f16)1.f};
            float sa = 0.f, sb = 0.f;
            #pragma unroll
            for (int q = 0; q < 4; ++q) { sa = fdot2f(pr[2*q], ones, sa); sb = fdot2f(pr[2*q+1], ones, sb); }
            l_own += sa + sb;
        }
    }

    l_own += __shfl_xor(l_own, 32);
    if (lane < 32) linv[mA + lane] = l_own;
    __syncthreads();
    if (tid < 128) {
        const float inv = 1.0f / (linv[tid] + pz);
        linv[tid] = inv;
        pzn[tid]  = pz * inv;
    }
    __syncthreads();

    #define EPI_TILE(CC, MI, NI) { \
        const int ch = (NI) * 16 + lr; \
        const float bv = bkv[128 + cb + ch]; \
        _Pragma("unroll") \
        for (int e = 0; e < 4; ++e) { \
            const int row = mA + (MI) * 16 + lg * 4 + e; \
            const float oo = fmaf(pzn[row], bv, CC[e] * linv[row]); \
            const int v2 = row >> 6, tt2 = (row >> 4) & 3, nn2 = (row >> 2) & 3, dd2 = row & 3; \
            const size_t tk = ((size_t)(v2 * 8 + t * 4 + tt2) * 1024 + n * 4 + nn2) * 4 + dd2; \
            o_out[tk * 128 + cb + ch] = (f16)oo; \
        } }
    EPI_TILE(oc00, 0, 0)
    EPI_TILE(oc01, 0, 1)
    EPI_TILE(oc10, 1, 0)
    EPI_TILE(oc11, 1, 1)
    #undef EPI_TILE
}

// ---------------- Kernel 2: MFMA epilogue, 64 tokens/block (unchanged) ----------------
__global__ __launch_bounds__(256, 3) void k_epi(
    const float* __restrict__ x, const f16* __restrict__ o_in,
    const float* __restrict__ bo, const float* __restrict__ gamma,
    const float* __restrict__ ln2_s, const float* __restrict__ ln2_b,
    const float* __restrict__ b1, const float* __restrict__ b2,
    const float* __restrict__ gm, float* __restrict__ out)
{
    __shared__ __align__(16) char smem[EPI_LDS];
    f16* eol    = (f16*)(smem + OFF_EOL);
    float* etv  = (float*)(smem + OFF_ETV);
    f16* eh2    = (f16*)(smem + OFF_EH2);
    float* erd  = (float*)(smem + OFF_ERD);
    f16* ehid   = eol;

    const f16* WoF = (const f16*)(g_wpack + OFF_WO);
    const f16* W1F = (const f16*)(g_wpack + OFF_W1);
    const f16* W2F = (const f16*)(g_wpack + OFF_W2);

    const int tid = threadIdx.x;
    const int lane = tid & 63, wv = tid >> 6;
    const int lr = lane & 15, lg = lane >> 4;
    const int mb = wv * 16;
    const size_t tok0 = (size_t)blockIdx.x * 64;

    {
        const int tk = tid >> 2, part = tid & 3;
        const f16x8* src = (const f16x8*)(o_in + (tok0 + tk) * 128 + part * 32);
        f16x8* dst = (f16x8*)(eol + tk * EOLS + part * 32);
        dst[0] = src[0]; dst[1] = src[1]; dst[2] = src[2]; dst[3] = src[3];
    }
    __syncthreads();

    {
        f16x8 a_[4];
        #pragma unroll
        for (int ks = 0; ks < 4; ++ks)
            a_[ks] = *(const f16x8*)(eol + (mb + lr) * EOLS + ks*32 + lg*8);
        #pragma unroll
        for (int nt = 0; nt < 4; ++nt) {
            const int ch = nt * 16 + lr;
            f32x4 c = {0.f,0.f,0.f,0.f};
            c = __builtin_amdgcn_mfma_f32_16x16x32_f16(a_[0], *(const f16x8*)(WoF + ch*128 +  0 + lg*8), c, 0, 0, 0);
            c = __builtin_amdgcn_mfma_f32_16x16x32_f16(a_[1], *(const f16x8*)(WoF + ch*128 + 32 + lg*8), c, 0, 0, 0);
            c = __builtin_amdgcn_mfma_f32_16x16x32_f16(a_[2], *(const f16x8*)(WoF + ch*128 + 64 + lg*8), c, 0, 0, 0);
            c = __builtin_amdgcn_mfma_f32_16x16x32_f16(a_[3], *(const f16x8*)(WoF + ch*128 + 96 + lg*8), c, 0, 0, 0);
            const float bo_c = bo[ch], ga_c = gamma[ch];
            #pragma unroll
            for (int e = 0; e < 4; ++e) {
                const int tk = mb + lg*4 + e;
                etv[tk * ETVS + ch] = x[(tok0 + tk)*64 + ch] + ga_c * (c[e] + bo_c);
            }
        }
    }
    __syncthreads();

    {
        const int tk = tid >> 2, q = tid & 3;
        const float* tr = etv + tk * ETVS + q * 16;
        float s1 = 0.f, s2 = 0.f;
        #pragma unroll
        for (int j = 0; j < 16; ++j) { const float v = tr[j]; s1 += v; s2 += v*v; }
        erd[(tk*4 + q)*2] = s1; erd[(tk*4 + q)*2 + 1] = s2;
    }
    __syncthreads();
    {
        const int tk = tid >> 2, q = tid & 3;
        float a1 = 0.f, a2 = 0.f;
        #pragma unroll
        for (int i = 0; i < 4; ++i) { a1 += erd[(tk*4 + i)*2]; a2 += erd[(tk*4 + i)*2 + 1]; }
        const float mean = a1 * 0.015625f;
        const float rstd = rsqrtf(a2 * 0.015625f - mean*mean + 1e-5f);
        const float* tr = etv + tk * ETVS + q * 16;
        f16* hr = eh2 + tk * EH2S + q * 16;
        #pragma unroll
        for (int j = 0; j < 16; ++j)
            hr[j] = (f16)((tr[j]-mean)*rstd*ln2_s[q*16 + j] + ln2_b[q*16 + j]);
    }
    __syncthreads();

    {
        f16x8 a_[2];
        #pragma unroll
        for (int ks = 0; ks < 2; ++ks)
            a_[ks] = *(const f16x8*)(eh2 + (mb + lr) * EH2S + ks*32 + lg*8);
        #pragma unroll
        for (int nt = 0; nt < 8; ++nt) {
            const int ch = nt * 16 + lr;
            f32x4 c = {0.f,0.f,0.f,0.f};
            c = __builtin_amdgcn_mfma_f32_16x16x32_f16(a_[0], *(const f16x8*)(W1F + ch*64 +  0 + lg*8), c, 0, 0, 0);
            c = __builtin_amdgcn_mfma_f32_16x16x32_f16(a_[1], *(const f16x8*)(W1F + ch*64 + 32 + lg*8), c, 0, 0, 0);
            const float b1_c = b1[ch];
            #pragma unroll
            for (int e = 0; e < 4; ++e) {
                const int tk = mb + lg*4 + e;
                const float z = c[e] + b1_c;
                const float u = 0.7978845608028654f * (z + 0.044715f * z*z*z);
                ehid[tk * EOLS + ch] = (f16)(z / (1.0f + exp2fast(-2.8853900817779268f * u)));
            }
        }
    }
    __syncthreads();

    {
        f16x8 a_[4];
        #pragma unroll
        for (int ks = 0; ks < 4; ++ks)
            a_[ks] = *(const f16x8*)(ehid + (mb + lr) * EOLS + ks*32 + lg*8);
        #pragma unroll
        for (int nt = 0; nt < 4; ++nt) {
            const int ch = nt * 16 + lr;
            f32x4 c = {0.f,0.f,0.f,0.f};
            c = __builtin_amdgcn_mfma_f32_16x16x32_f16(a_[0], *(const f16x8*)(W2F + ch*128 +  0 + lg*8), c, 0, 0, 0);
            c = __builtin_amdgcn_mfma_f32_16x16x32_f16(a_[1], *(const f16x8*)(W2F + ch*128 + 32 + lg*8), c, 0, 0, 0);
            c = __builtin_amdgcn_mfma_f32_16x16x32_f16(a_[2], *(const f16x8*)(W2F + ch*128 + 64 + lg*8), c, 0, 0, 0);
            c = __builtin_amdgcn_mfma_f32_16x16x32_f16(a_[3], *(const f16x8*)(W2F + ch*128 + 96 + lg*8), c, 0, 0, 0);
            const float b2_c = b2[ch], gm_c = gm[ch];
            #pragma unroll
            for (int e = 0; e < 4; ++e) {
                const int tk = mb + lg*4 + e;
                out[(tok0 + tk)*64 + ch] = etv[tk * ETVS + ch] + gm_c * (c[e] + b2_c);
            }
        }
    }
}

extern "C" void kernel_launch(void* const* d_in, const int* in_sizes, int n_in,
                              void* d_out, int out_size, void* d_ws, size_t ws_size,
                              hipStream_t stream) {
    const float* x        = (const float*)d_in[0];
    const float* ln1_s    = (const float*)d_in[1];
    const float* ln1_b    = (const float*)d_in[2];
    const float* Wq       = (const float*)d_in[3];
    const float* Wkv      = (const float*)d_in[4];
    const float* bkv      = (const float*)d_in[5];
    const float* Wo       = (const float*)d_in[6];
    const float* bo       = (const float*)d_in[7];
    const float* gamma    = (const float*)d_in[8];
    const float* ln2_s    = (const float*)d_in[9];
    const float* ln2_b    = (const float*)d_in[10];
    const float* W1       = (const float*)d_in[11];
    const float* b1       = (const float*)d_in[12];
    const float* W2       = (const float*)d_in[13];
    const float* b2       = (const float*)d_in[14];
    const float* gamma_mlp= (const float*)d_in[15];

    // o (f16[65536][128]) aliases d_out (f32[65536][64]); disjoint token partition
    // between k_att writes and k_epi reads/overwrites -> race-free.
    f16* o_buf = (f16*)d_out;
    float* out = (float*)d_out;

    hipLaunchKernelGGL(k_conv, dim3(NPAIRS / 256), dim3(256), 0, stream,
                       Wq, Wkv, Wo, W1, W2);
    hipLaunchKernelGGL(k_ln, dim3(256), dim3(256), 0, stream,
                       x, ln1_s, ln1_b);
    hipLaunchKernelGGL(k_att, dim3(2048), dim3(256), 0, stream,
                       bkv, o_buf);
    hipLaunchKernelGGL(k_epi, dim3(1024), dim3(256), 0, stream,
                       x, o_buf, bo, gamma, ln2_s, ln2_b, b1, b2, gamma_mlp, out);
}

// Round 20
// 86.912 us; speedup vs baseline: 1.0320x; 1.0320x over previous
//
#include <hip/hip_runtime.h>
#include <math.h>

typedef _Float16 f16;
typedef _Float16 f16x2 __attribute__((ext_vector_type(2)));
typedef _Float16 f16x4 __attribute__((ext_vector_type(4)));
typedef _Float16 f16x8 __attribute__((ext_vector_type(8)));
typedef float f32x4 __attribute__((ext_vector_type(4)));

#if defined(__has_builtin)
#if __has_builtin(__builtin_amdgcn_fdot2)
#define USE_FDOT2 1
#endif
#if __has_builtin(__builtin_amdgcn_exp2f)
#define USE_EXP2 1
#endif
#endif

__device__ __forceinline__ float fdot2f(f16x2 a, f16x2 b, float c) {
#ifdef USE_FDOT2
    return __builtin_amdgcn_fdot2(a, b, c, false);
#else
    return c + (float)a.x * (float)b.x + (float)a.y * (float)b.y;
#endif
}
__device__ __forceinline__ float exp2fast(float a) {
#ifdef USE_EXP2
    return __builtin_amdgcn_exp2f(a);
#else
    return exp2f(a);
#endif
}

namespace {
// ---- k_att constants (r19: wave-local softmax finalize; 1 barrier) ----
constexpr int KS  = 40;
constexpr int QLS = 40;
constexpr int VTS = 200;
constexpr int PSW = 40;
constexpr int OFF_KL = 0;            // 192*40*2 = 15360
constexpr int OFF_VT = 15360;        // 12800 -> 28160
constexpr int OFF_QL = 28160;        // 10240 -> 38400
constexpr int OFF_PW = 38400;        // 10240 -> 48640
constexpr int ATT_LDS = 48640;       // x3 = 145920 < 160K -> 3 blocks/CU
constexpr float C1  = 0.2550600f;
constexpr float CZN = -5.7707801f;
constexpr float CZV = 2.5511480f;

// ---- packed-f16 weights: P[out][in/2] f16x2 pairs; row o = W[:,o] = B-fragment row o
constexpr int OFF_WQ  = 0;
constexpr int OFF_WKV = 4096;
constexpr int OFF_WO  = 12288;
constexpr int OFF_W1  = 16384;
constexpr int OFF_W2  = 20480;
constexpr int NPAIRS  = 24576;

// ---- k_epi constants (unchanged) ----
constexpr int EOLS = 136;
constexpr int ETVS = 66;
constexpr int EH2S = 72;
constexpr int OFF_EOL = 0;
constexpr int OFF_ETV = 17408;
constexpr int OFF_EH2 = 34304;
constexpr int OFF_ERD = 43520;
constexpr int EPI_LDS = 45568;
}

__device__ f16x2 g_wpack[NPAIRS];
__device__ f16 g_h[65536 * 64];      // LN1'd tokens, f16 (8.4 MB device global)

// ---------------- Kernel 0: pack GEMV weights to f16x2 ----------------
__global__ void k_conv(const float* __restrict__ Wq, const float* __restrict__ Wkv,
                       const float* __restrict__ Wo, const float* __restrict__ W1,
                       const float* __restrict__ W2) {
    const int i = blockIdx.x * 256 + threadIdx.x;
    const float* src; int inp, out, base;
    if (i < OFF_WKV)     { src = Wq;  inp = 32; out = 128; base = OFF_WQ;  }
    else if (i < OFF_WO) { src = Wkv; inp = 32; out = 256; base = OFF_WKV; }
    else if (i < OFF_W1) { src = Wo;  inp = 64; out = 64;  base = OFF_WO;  }
    else if (i < OFF_W2) { src = W1;  inp = 32; out = 128; base = OFF_W1;  }
    else                 { src = W2;  inp = 64; out = 64;  base = OFF_W2;  }
    const int li = i - base;
    const int o = li / inp, p = li % inp;
    g_wpack[i] = (f16x2){(f16)src[(2*p) * out + o], (f16)src[(2*p+1) * out + o]};
}

// ---------------- Kernel 0b: LN1 -> g_h. r19: zero-LDS, 4 threads/token ----------------
// r18's version used 66KB LDS at 256 blocks (2/CU, 1 round -> runtime = serial block
// latency ~15-20us). Now: 1024 blocks, 4-lane-group shuffle reduction, no LDS.
__global__ __launch_bounds__(256, 8) void k_ln(
    const float* __restrict__ x,
    const float* __restrict__ ln1_s, const float* __restrict__ ln1_b) {
    const int tid = threadIdx.x;
    const size_t tok = (size_t)blockIdx.x * 64 + (tid >> 2);
    const int q = tid & 3;
    const float* xr = x + tok * 64 + q * 16;
    float v[16];
    {
        const float4 a = ((const float4*)xr)[0], b = ((const float4*)xr)[1];
        const float4 c = ((const float4*)xr)[2], d = ((const float4*)xr)[3];
        v[0]=a.x; v[1]=a.y; v[2]=a.z; v[3]=a.w;  v[4]=b.x; v[5]=b.y; v[6]=b.z; v[7]=b.w;
        v[8]=c.x; v[9]=c.y; v[10]=c.z; v[11]=c.w; v[12]=d.x; v[13]=d.y; v[14]=d.z; v[15]=d.w;
    }
    float s = 0.f, ss = 0.f;
    #pragma unroll
    for (int j = 0; j < 16; ++j) { s += v[j]; ss += v[j]*v[j]; }
    s  += __shfl_xor(s, 1);  s  += __shfl_xor(s, 2);
    ss += __shfl_xor(ss, 1); ss += __shfl_xor(ss, 2);
    const float mean = s * 0.015625f;
    const float rstd = rsqrtf(ss * 0.015625f - mean*mean + 1e-5f);
    f16x8 p0, p1;
    #pragma unroll
    for (int j = 0; j < 8; ++j) {
        p0[j] = (f16)((v[j]     - mean) * rstd * ln1_s[q*16 + j]     + ln1_b[q*16 + j]);
        p1[j] = (f16)((v[j + 8] - mean) * rstd * ln1_s[q*16 + j + 8] + ln1_b[q*16 + j + 8]);
    }
    f16* hr = g_h + tok * 64 + q * 16;
    ((f16x8*)hr)[0] = p0;
    ((f16x8*)hr)[1] = p1;
}

// ---------------- Kernel 1: per-(window,head) attention; A-frags from g_h ----------------
// r19: pz/l/inv finalize is wave-local (rows mA..mA+31 owned by wave wv) via shuffles;
// linv/pzn LDS buffers and 2 barriers removed. 1 barrier total (after Phase C).
__global__ __launch_bounds__(256, 3) void k_att(
    const float* __restrict__ bkv,
    f16* __restrict__ o_out)
{
    __shared__ __align__(16) char smem[ATT_LDS];
    f16* kl   = (f16*)(smem + OFF_KL);
    f16* vt   = (f16*)(smem + OFF_VT);
    f16* ql   = (f16*)(smem + OFF_QL);

    const int tid  = threadIdx.x;
    const int bid  = blockIdx.x;
    const int w    = bid & 511;
    const int head = bid >> 9;
    const int cb   = head * 32;
    const int n    = w & 255;
    const int t    = w >> 8;

    const int lane = tid & 63, wv = tid >> 6;
    const int lr = lane & 15, lg = lane >> 4;

    const f16* WqF  = (const f16*)(g_wpack + OFF_WQ);
    const f16* WkvF = (const f16*)(g_wpack + OFF_WKV);

    // Phase C: MFMA projections; A-fragments read directly from g_h
    {
        #pragma unroll
        for (int mi = 0; mi < 3; ++mi) {
            const int seg = wv * 3 + mi;                    // 0..11
            const int v_ = seg / 6;
            const int t2 = (seg % 6) + ((t == 0) ? 2 : 0);
            int tsrc, tt;
            if (t2 < 2)      { tsrc = t - 1; tt = t2 + 2; }
            else if (t2 < 6) { tsrc = t;     tt = t2 - 2; }
            else             { tsrc = t + 1; tt = t2 - 6; }
            const size_t tb = (size_t)(v_ * 8 + tsrc * 4 + tt) * 4096 + n * 16;
            const int mb = seg * 16;
            #pragma unroll
            for (int nt = 0; nt < 2; ++nt) {
                f32x4 ck = {0.f,0.f,0.f,0.f}, cv = {0.f,0.f,0.f,0.f};
                #pragma unroll
                for (int ks = 0; ks < 2; ++ks) {
                    const f16x8 af = *(const f16x8*)(g_h + (tb + lr) * 64 + ks*32 + lg*8);
                    const f16x8 bk = *(const f16x8*)(WkvF + (cb + nt*16 + lr)*64 + ks*32 + lg*8);
                    const f16x8 bv = *(const f16x8*)(WkvF + (128 + cb + nt*16 + lr)*64 + ks*32 + lg*8);
                    ck = __builtin_amdgcn_mfma_f32_16x16x32_f16(af, bk, ck, 0, 0, 0);
                    cv = __builtin_amdgcn_mfma_f32_16x16x32_f16(af, bv, cv, 0, 0, 0);
                }
                const float bk_b = bkv[cb + nt*16 + lr];
                const float bv_b = bkv[128 + cb + nt*16 + lr];
                #pragma unroll
                for (int e = 0; e < 4; ++e) {
                    const int row = mb + lg*4 + e;
                    kl[row * KS + nt*16 + lr] = (f16)(ck[e] + bk_b);
                    vt[(nt*16 + lr) * VTS + row] = (f16)(cv[e] + bv_b);
                }
            }
        }
        #pragma unroll
        for (int mi = 0; mi < 2; ++mi) {
            const int qm = wv * 2 + mi;                     // 0..7
            const int v_ = qm >> 2, tt = qm & 3;
            const size_t tb = (size_t)(v_ * 8 + t * 4 + tt) * 4096 + n * 16;
            const int qb = v_ * 64 + tt * 16;
            #pragma unroll
            for (int nt = 0; nt < 2; ++nt) {
                f32x4 cq = {0.f,0.f,0.f,0.f};
                #pragma unroll
                for (int ks = 0; ks < 2; ++ks) {
                    const f16x8 af = *(const f16x8*)(g_h + (tb + lr) * 64 + ks*32 + lg*8);
                    const f16x8 bq = *(const f16x8*)(WqF + (cb + nt*16 + lr)*64 + ks*32 + lg*8);
                    cq = __builtin_amdgcn_mfma_f32_16x16x32_f16(af, bq, cq, 0, 0, 0);
                }
                #pragma unroll
                for (int e = 0; e < 4; ++e)
                    ql[(qb + lg*4 + e) * QLS + nt*16 + lr] = (f16)cq[e];
            }
        }
    }
    __syncthreads();   // kl/vt/ql ready (the kernel's only barrier)

    const int mA = wv * 32;
    f16* Pw = (f16*)(smem + OFF_PW) + wv * 32 * PSW;
    const int prow = lane & 31, pcolh = lane >> 5;

    // pz for this wave's row mA+(lane&31), computed on all lanes (halves duplicate)
    float pz;
    {
        const f16x2* qr2 = (const f16x2*)(ql + (mA + prow) * QLS);
        float sz = 0.f;
        #pragma unroll
        for (int j = 0; j < 16; ++j)
            sz += (float)qr2[j].x * bkv[cb + 2*j] + (float)qr2[j].y * bkv[cb + 2*j + 1];
        pz = exp2fast(fmaf(sz, C1, CZV));
    }

    f32x4 oc00 = {0.f,0.f,0.f,0.f}, oc01 = {0.f,0.f,0.f,0.f};
    f32x4 oc10 = {0.f,0.f,0.f,0.f}, oc11 = {0.f,0.f,0.f,0.f};
    float l_own = 0.f;

    #pragma unroll 1
    for (int kk = 0; kk < 6; ++kk) {
        #pragma unroll
        for (int mi = 0; mi < 2; ++mi) {
            const f16x8 af = *(const f16x8*)(ql + (mA + mi*16 + lr) * QLS + lg * 8);
            #pragma unroll
            for (int nt = 0; nt < 2; ++nt) {
                const f16x8 bf = *(const f16x8*)(kl + (kk*32 + nt*16 + lr) * KS + lg * 8);
                const f32x4 c = __builtin_amdgcn_mfma_f32_16x16x32_f16(af, bf, (f32x4){0.f,0.f,0.f,0.f}, 0, 0, 0);
                #pragma unroll
                for (int e = 0; e < 4; ++e)
                    Pw[(mi*16 + lg*4 + e) * PSW + nt*16 + lr] = (f16)exp2fast(fmaf(c[e], C1, CZN));
            }
        }
        const f16x8 a0 = *(const f16x8*)(Pw + lr * PSW + lg * 8);
        const f16x8 a1 = *(const f16x8*)(Pw + (16 + lr) * PSW + lg * 8);
        const f16x8 b0 = *(const f16x8*)(vt + lr * VTS + kk*32 + lg*8);
        const f16x8 b1 = *(const f16x8*)(vt + (16 + lr) * VTS + kk*32 + lg*8);
        oc00 = __builtin_amdgcn_mfma_f32_16x16x32_f16(a0, b0, oc00, 0, 0, 0);
        oc01 = __builtin_amdgcn_mfma_f32_16x16x32_f16(a0, b1, oc01, 0, 0, 0);
        oc10 = __builtin_amdgcn_mfma_f32_16x16x32_f16(a1, b0, oc10, 0, 0, 0);
        oc11 = __builtin_amdgcn_mfma_f32_16x16x32_f16(a1, b1, oc11, 0, 0, 0);
        {
            const f16x2* pr = (const f16x2*)(Pw + prow * PSW + pcolh * 16);
            const f16x2 ones = (f16x2){(f16)1.f, (f16)1.f};
            float sa = 0.f, sb = 0.f;
            #pragma unroll
            for (int q = 0; q < 4; ++q) { sa = fdot2f(pr[2*q], ones, sa); sb = fdot2f(pr[2*q+1], ones, sb); }
            l_own += sa + sb;
        }
    }

    l_own += __shfl_xor(l_own, 32);                 // full row sum for row mA+prow
    const float inv_r = 1.0f / (l_own + pz);        // lane k (k&31) holds row mA+(k&31)
    const float pzn_r = pz * inv_r;

    // epilogue: O = C*inv[row] + pzn[row]*bkv_v[col]; row factors via wave shuffle
    #define EPI_TILE(CC, MI, NI) { \
        const int ch = (NI) * 16 + lr; \
        const float bv = bkv[128 + cb + ch]; \
        _Pragma("unroll") \
        for (int e = 0; e < 4; ++e) { \
            const int ridx = (MI) * 16 + lg * 4 + e; \
            const float invr = __shfl(inv_r, ridx); \
            const float pznr = __shfl(pzn_r, ridx); \
            const int row = mA + ridx; \
            const float oo = fmaf(pznr, bv, CC[e] * invr); \
            const int v2 = row >> 6, tt2 = (row >> 4) & 3, nn2 = (row >> 2) & 3, dd2 = row & 3; \
            const size_t tk = ((size_t)(v2 * 8 + t * 4 + tt2) * 1024 + n * 4 + nn2) * 4 + dd2; \
            o_out[tk * 128 + cb + ch] = (f16)oo; \
        } }
    EPI_TILE(oc00, 0, 0)
    EPI_TILE(oc01, 0, 1)
    EPI_TILE(oc10, 1, 0)
    EPI_TILE(oc11, 1, 1)
    #undef EPI_TILE
}

// ---------------- Kernel 2: MFMA epilogue, 64 tokens/block (unchanged) ----------------
__global__ __launch_bounds__(256, 3) void k_epi(
    const float* __restrict__ x, const f16* __restrict__ o_in,
    const float* __restrict__ bo, const float* __restrict__ gamma,
    const float* __restrict__ ln2_s, const float* __restrict__ ln2_b,
    const float* __restrict__ b1, const float* __restrict__ b2,
    const float* __restrict__ gm, float* __restrict__ out)
{
    __shared__ __align__(16) char smem[EPI_LDS];
    f16* eol    = (f16*)(smem + OFF_EOL);
    float* etv  = (float*)(smem + OFF_ETV);
    f16* eh2    = (f16*)(smem + OFF_EH2);
    float* erd  = (float*)(smem + OFF_ERD);
    f16* ehid   = eol;

    const f16* WoF = (const f16*)(g_wpack + OFF_WO);
    const f16* W1F = (const f16*)(g_wpack + OFF_W1);
    const f16* W2F = (const f16*)(g_wpack + OFF_W2);

    const int tid = threadIdx.x;
    const int lane = tid & 63, wv = tid >> 6;
    const int lr = lane & 15, lg = lane >> 4;
    const int mb = wv * 16;
    const size_t tok0 = (size_t)blockIdx.x * 64;

    {
        const int tk = tid >> 2, part = tid & 3;
        const f16x8* src = (const f16x8*)(o_in + (tok0 + tk) * 128 + part * 32);
        f16x8* dst = (f16x8*)(eol + tk * EOLS + part * 32);
        dst[0] = src[0]; dst[1] = src[1]; dst[2] = src[2]; dst[3] = src[3];
    }
    __syncthreads();

    {
        f16x8 a_[4];
        #pragma unroll
        for (int ks = 0; ks < 4; ++ks)
            a_[ks] = *(const f16x8*)(eol + (mb + lr) * EOLS + ks*32 + lg*8);
        #pragma unroll
        for (int nt = 0; nt < 4; ++nt) {
            const int ch = nt * 16 + lr;
            f32x4 c = {0.f,0.f,0.f,0.f};
            c = __builtin_amdgcn_mfma_f32_16x16x32_f16(a_[0], *(const f16x8*)(WoF + ch*128 +  0 + lg*8), c, 0, 0, 0);
            c = __builtin_amdgcn_mfma_f32_16x16x32_f16(a_[1], *(const f16x8*)(WoF + ch*128 + 32 + lg*8), c, 0, 0, 0);
            c = __builtin_amdgcn_mfma_f32_16x16x32_f16(a_[2], *(const f16x8*)(WoF + ch*128 + 64 + lg*8), c, 0, 0, 0);
            c = __builtin_amdgcn_mfma_f32_16x16x32_f16(a_[3], *(const f16x8*)(WoF + ch*128 + 96 + lg*8), c, 0, 0, 0);
            const float bo_c = bo[ch], ga_c = gamma[ch];
            #pragma unroll
            for (int e = 0; e < 4; ++e) {
                const int tk = mb + lg*4 + e;
                etv[tk * ETVS + ch] = x[(tok0 + tk)*64 + ch] + ga_c * (c[e] + bo_c);
            }
        }
    }
    __syncthreads();

    {
        const int tk = tid >> 2, q = tid & 3;
        const float* tr = etv + tk * ETVS + q * 16;
        float s1 = 0.f, s2 = 0.f;
        #pragma unroll
        for (int j = 0; j < 16; ++j) { const float v = tr[j]; s1 += v; s2 += v*v; }
        erd[(tk*4 + q)*2] = s1; erd[(tk*4 + q)*2 + 1] = s2;
    }
    __syncthreads();
    {
        const int tk = tid >> 2, q = tid & 3;
        float a1 = 0.f, a2 = 0.f;
        #pragma unroll
        for (int i = 0; i < 4; ++i) { a1 += erd[(tk*4 + i)*2]; a2 += erd[(tk*4 + i)*2 + 1]; }
        const float mean = a1 * 0.015625f;
        const float rstd = rsqrtf(a2 * 0.015625f - mean*mean + 1e-5f);
        const float* tr = etv + tk * ETVS + q * 16;
        f16* hr = eh2 + tk * EH2S + q * 16;
        #pragma unroll
        for (int j = 0; j < 16; ++j)
            hr[j] = (f16)((tr[j]-mean)*rstd*ln2_s[q*16 + j] + ln2_b[q*16 + j]);
    }
    __syncthreads();

    {
        f16x8 a_[2];
        #pragma unroll
        for (int ks = 0; ks < 2; ++ks)
            a_[ks] = *(const f16x8*)(eh2 + (mb + lr) * EH2S + ks*32 + lg*8);
        #pragma unroll
        for (int nt = 0; nt < 8; ++nt) {
            const int ch = nt * 16 + lr;
            f32x4 c = {0.f,0.f,0.f,0.f};
            c = __builtin_amdgcn_mfma_f32_16x16x32_f16(a_[0], *(const f16x8*)(W1F + ch*64 +  0 + lg*8), c, 0, 0, 0);
            c = __builtin_amdgcn_mfma_f32_16x16x32_f16(a_[1], *(const f16x8*)(W1F + ch*64 + 32 + lg*8), c, 0, 0, 0);
            const float b1_c = b1[ch];
            #pragma unroll
            for (int e = 0; e < 4; ++e) {
                const int tk = mb + lg*4 + e;
                const float z = c[e] + b1_c;
                const float u = 0.7978845608028654f * (z + 0.044715f * z*z*z);
                ehid[tk * EOLS + ch] = (f16)(z / (1.0f + exp2fast(-2.8853900817779268f * u)));
            }
        }
    }
    __syncthreads();

    {
        f16x8 a_[4];
        #pragma unroll
        for (int ks = 0; ks < 4; ++ks)
            a_[ks] = *(const f16x8*)(ehid + (mb + lr) * EOLS + ks*32 + lg*8);
        #pragma unroll
        for (int nt = 0; nt < 4; ++nt) {
            const int ch = nt * 16 + lr;
            f32x4 c = {0.f,0.f,0.f,0.f};
            c = __builtin_amdgcn_mfma_f32_16x16x32_f16(a_[0], *(const f16x8*)(W2F + ch*128 +  0 + lg*8), c, 0, 0, 0);
            c = __builtin_amdgcn_mfma_f32_16x16x32_f16(a_[1], *(const f16x8*)(W2F + ch*128 + 32 + lg*8), c, 0, 0, 0);
            c = __builtin_amdgcn_mfma_f32_16x16x32_f16(a_[2], *(const f16x8*)(W2F + ch*128 + 64 + lg*8), c, 0, 0, 0);
            c = __builtin_amdgcn_mfma_f32_16x16x32_f16(a_[3], *(const f16x8*)(W2F + ch*128 + 96 + lg*8), c, 0, 0, 0);
            const float b2_c = b2[ch], gm_c = gm[ch];
            #pragma unroll
            for (int e = 0; e < 4; ++e) {
                const int tk = mb + lg*4 + e;
                out[(tok0 + tk)*64 + ch] = etv[tk * ETVS + ch] + gm_c * (c[e] + b2_c);
            }
        }
    }
}

extern "C" void kernel_launch(void* const* d_in, const int* in_sizes, int n_in,
                              void* d_out, int out_size, void* d_ws, size_t ws_size,
                              hipStream_t stream) {
    const float* x        = (const float*)d_in[0];
    const float* ln1_s    = (const float*)d_in[1];
    const float* ln1_b    = (const float*)d_in[2];
    const float* Wq       = (const float*)d_in[3];
    const float* Wkv      = (const float*)d_in[4];
    const float* bkv      = (const float*)d_in[5];
    const float* Wo       = (const float*)d_in[6];
    const float* bo       = (const float*)d_in[7];
    const float* gamma    = (const float*)d_in[8];
    const float* ln2_s    = (const float*)d_in[9];
    const float* ln2_b    = (const float*)d_in[10];
    const float* W1       = (const float*)d_in[11];
    const float* b1       = (const float*)d_in[12];
    const float* W2       = (const float*)d_in[13];
    const float* b2       = (const float*)d_in[14];
    const float* gamma_mlp= (const float*)d_in[15];

    // o (f16[65536][128]) aliases d_out (f32[65536][64]); disjoint token partition
    // between k_att writes and k_epi reads/overwrites -> race-free.
    f16* o_buf = (f16*)d_out;
    float* out = (float*)d_out;

    hipLaunchKernelGGL(k_conv, dim3(NPAIRS / 256), dim3(256), 0, stream,
                       Wq, Wkv, Wo, W1, W2);
    hipLaunchKernelGGL(k_ln, dim3(1024), dim3(256), 0, stream,
                       x, ln1_s, ln1_b);
    hipLaunchKernelGGL(k_att, dim3(2048), dim3(256), 0, stream,
                       bkv, o_buf);
    hipLaunchKernelGGL(k_epi, dim3(1024), dim3(256), 0, stream,
                       x, o_buf, bo, gamma, ln2_s, ln2_b, b1, b2, gamma_mlp, out);
}

// Round 22
// 86.234 us; speedup vs baseline: 1.0401x; 1.0079x over previous
//
#include <hip/hip_runtime.h>
#include <math.h>

typedef _Float16 f16;
typedef _Float16 f16x2 __attribute__((ext_vector_type(2)));
typedef _Float16 f16x4 __attribute__((ext_vector_type(4)));
typedef _Float16 f16x8 __attribute__((ext_vector_type(8)));
typedef float f32x4 __attribute__((ext_vector_type(4)));

#if defined(__has_builtin)
#if __has_builtin(__builtin_amdgcn_fdot2)
#define USE_FDOT2 1
#endif
#if __has_builtin(__builtin_amdgcn_exp2f)
#define USE_EXP2 1
#endif
#if __has_builtin(__builtin_amdgcn_cvt_pkrtz)
#define USE_PKRTZ 1
#endif
#endif

__device__ __forceinline__ float fdot2f(f16x2 a, f16x2 b, float c) {
#ifdef USE_FDOT2
    return __builtin_amdgcn_fdot2(a, b, c, false);
#else
    return c + (float)a.x * (float)b.x + (float)a.y * (float)b.y;
#endif
}
__device__ __forceinline__ float exp2fast(float a) {
#ifdef USE_EXP2
    return __builtin_amdgcn_exp2f(a);
#else
    return exp2f(a);
#endif
}
__device__ __forceinline__ f16x2 pk2(float a, float b) {
#ifdef USE_PKRTZ
    // builtin returns __fp16 ext_vector(2); bit-cast to our _Float16 vector type
    // (r21 compile fix: no implicit conversion between the two).
    auto r0 = __builtin_amdgcn_cvt_pkrtz(a, b);
    f16x2 r; __builtin_memcpy(&r, &r0, 4); return r;
#else
    return (f16x2){(f16)a, (f16)b};
#endif
}
__device__ __forceinline__ int f16x2_as_int(f16x2 v) { int r; __builtin_memcpy(&r, &v, 4); return r; }
__device__ __forceinline__ f16x2 int_as_f16x2(int v) { f16x2 r; __builtin_memcpy(&r, &v, 4); return r; }

namespace {
// ---- k_att constants (register-resident P via shuffle transpose; no Pw) ----
constexpr int KS  = 40;
constexpr int QLS = 40;
constexpr int VTS = 200;
constexpr int OFF_KL = 0;            // 192*40*2 = 15360
constexpr int OFF_VT = 15360;        // 12800 -> 28160
constexpr int OFF_QL = 28160;        // 10240 -> 38400
constexpr int ATT_LDS = 38400;       // x4 = 153600 <= 160K -> 4 blocks/CU
constexpr float C1  = 0.2550600f;
constexpr float CZN = -5.7707801f;
constexpr float CZV = 2.5511480f;

// ---- packed-f16 weights: P[out][in/2] f16x2 pairs; row o = W[:,o] = B-fragment row o
constexpr int OFF_WQ  = 0;
constexpr int OFF_WKV = 4096;
constexpr int OFF_WO  = 12288;
constexpr int OFF_W1  = 16384;
constexpr int OFF_W2  = 20480;
constexpr int NPAIRS  = 24576;

// ---- k_epi constants (unchanged) ----
constexpr int EOLS = 136;
constexpr int ETVS = 66;
constexpr int EH2S = 72;
constexpr int OFF_EOL = 0;
constexpr int OFF_ETV = 17408;
constexpr int OFF_EH2 = 34304;
constexpr int OFF_ERD = 43520;
constexpr int EPI_LDS = 45568;
}

__device__ f16x2 g_wpack[NPAIRS];
__device__ f16 g_h[65536 * 64];      // LN1'd tokens, f16 (8.4 MB device global)

// ---------------- Kernel 0: pack GEMV weights to f16x2 ----------------
__global__ void k_conv(const float* __restrict__ Wq, const float* __restrict__ Wkv,
                       const float* __restrict__ Wo, const float* __restrict__ W1,
                       const float* __restrict__ W2) {
    const int i = blockIdx.x * 256 + threadIdx.x;
    const float* src; int inp, out, base;
    if (i < OFF_WKV)     { src = Wq;  inp = 32; out = 128; base = OFF_WQ;  }
    else if (i < OFF_WO) { src = Wkv; inp = 32; out = 256; base = OFF_WKV; }
    else if (i < OFF_W1) { src = Wo;  inp = 64; out = 64;  base = OFF_WO;  }
    else if (i < OFF_W2) { src = W1;  inp = 32; out = 128; base = OFF_W1;  }
    else                 { src = W2;  inp = 64; out = 64;  base = OFF_W2;  }
    const int li = i - base;
    const int o = li / inp, p = li % inp;
    g_wpack[i] = (f16x2){(f16)src[(2*p) * out + o], (f16)src[(2*p+1) * out + o]};
}

// ---------------- Kernel 0b: LN1 -> g_h. zero-LDS, 4 threads/token ----------------
__global__ __launch_bounds__(256, 8) void k_ln(
    const float* __restrict__ x,
    const float* __restrict__ ln1_s, const float* __restrict__ ln1_b) {
    const int tid = threadIdx.x;
    const size_t tok = (size_t)blockIdx.x * 64 + (tid >> 2);
    const int q = tid & 3;
    const float* xr = x + tok * 64 + q * 16;
    float v[16];
    {
        const float4 a = ((const float4*)xr)[0], b = ((const float4*)xr)[1];
        const float4 c = ((const float4*)xr)[2], d = ((const float4*)xr)[3];
        v[0]=a.x; v[1]=a.y; v[2]=a.z; v[3]=a.w;  v[4]=b.x; v[5]=b.y; v[6]=b.z; v[7]=b.w;
        v[8]=c.x; v[9]=c.y; v[10]=c.z; v[11]=c.w; v[12]=d.x; v[13]=d.y; v[14]=d.z; v[15]=d.w;
    }
    float s = 0.f, ss = 0.f;
    #pragma unroll
    for (int j = 0; j < 16; ++j) { s += v[j]; ss += v[j]*v[j]; }
    s  += __shfl_xor(s, 1);  s  += __shfl_xor(s, 2);
    ss += __shfl_xor(ss, 1); ss += __shfl_xor(ss, 2);
    const float mean = s * 0.015625f;
    const float rstd = rsqrtf(ss * 0.015625f - mean*mean + 1e-5f);
    f16x8 p0, p1;
    #pragma unroll
    for (int j = 0; j < 8; ++j) {
        p0[j] = (f16)((v[j]     - mean) * rstd * ln1_s[q*16 + j]     + ln1_b[q*16 + j]);
        p1[j] = (f16)((v[j + 8] - mean) * rstd * ln1_s[q*16 + j + 8] + ln1_b[q*16 + j + 8]);
    }
    f16* hr = g_h + tok * 64 + q * 16;
    ((f16x8*)hr)[0] = p0;
    ((f16x8*)hr)[1] = p1;
}

// ---------------- Kernel 1: per-(window,head) attention; P in registers ----------------
__global__ __launch_bounds__(256, 4) void k_att(
    const float* __restrict__ bkv,
    f16* __restrict__ o_out)
{
    __shared__ __align__(16) char smem[ATT_LDS];
    f16* kl   = (f16*)(smem + OFF_KL);
    f16* vt   = (f16*)(smem + OFF_VT);
    f16* ql   = (f16*)(smem + OFF_QL);

    const int tid  = threadIdx.x;
    const int bid  = blockIdx.x;
    const int w    = bid & 511;
    const int head = bid >> 9;
    const int cb   = head * 32;
    const int n    = w & 255;
    const int t    = w >> 8;

    const int lane = tid & 63, wv = tid >> 6;
    const int lr = lane & 15, lg = lane >> 4;

    const f16* WqF  = (const f16*)(g_wpack + OFF_WQ);
    const f16* WkvF = (const f16*)(g_wpack + OFF_WKV);

    // Phase C: MFMA projections; A-fragments read directly from g_h
    {
        #pragma unroll
        for (int mi = 0; mi < 3; ++mi) {
            const int seg = wv * 3 + mi;                    // 0..11
            const int v_ = seg / 6;
            const int t2 = (seg % 6) + ((t == 0) ? 2 : 0);
            int tsrc, tt;
            if (t2 < 2)      { tsrc = t - 1; tt = t2 + 2; }
            else if (t2 < 6) { tsrc = t;     tt = t2 - 2; }
            else             { tsrc = t + 1; tt = t2 - 6; }
            const size_t tb = (size_t)(v_ * 8 + tsrc * 4 + tt) * 4096 + n * 16;
            const int mb = seg * 16;
            #pragma unroll
            for (int nt = 0; nt < 2; ++nt) {
                f32x4 ck = {0.f,0.f,0.f,0.f}, cv = {0.f,0.f,0.f,0.f};
                #pragma unroll
                for (int ks = 0; ks < 2; ++ks) {
                    const f16x8 af = *(const f16x8*)(g_h + (tb + lr) * 64 + ks*32 + lg*8);
                    const f16x8 bk = *(const f16x8*)(WkvF + (cb + nt*16 + lr)*64 + ks*32 + lg*8);
                    const f16x8 bv = *(const f16x8*)(WkvF + (128 + cb + nt*16 + lr)*64 + ks*32 + lg*8);
                    ck = __builtin_amdgcn_mfma_f32_16x16x32_f16(af, bk, ck, 0, 0, 0);
                    cv = __builtin_amdgcn_mfma_f32_16x16x32_f16(af, bv, cv, 0, 0, 0);
                }
                const float bk_b = bkv[cb + nt*16 + lr];
                const float bv_b = bkv[128 + cb + nt*16 + lr];
                #pragma unroll
                for (int e = 0; e < 4; ++e) {
                    const int row = mb + lg*4 + e;
                    kl[row * KS + nt*16 + lr] = (f16)(ck[e] + bk_b);
                    vt[(nt*16 + lr) * VTS + row] = (f16)(cv[e] + bv_b);
                }
            }
        }
        #pragma unroll
        for (int mi = 0; mi < 2; ++mi) {
            const int qm = wv * 2 + mi;                     // 0..7
            const int v_ = qm >> 2, tt = qm & 3;
            const size_t tb = (size_t)(v_ * 8 + t * 4 + tt) * 4096 + n * 16;
            const int qb = v_ * 64 + tt * 16;
            #pragma unroll
            for (int nt = 0; nt < 2; ++nt) {
                f32x4 cq = {0.f,0.f,0.f,0.f};
                #pragma unroll
                for (int ks = 0; ks < 2; ++ks) {
                    const f16x8 af = *(const f16x8*)(g_h + (tb + lr) * 64 + ks*32 + lg*8);
                    const f16x8 bq = *(const f16x8*)(WqF + (cb + nt*16 + lr)*64 + ks*32 + lg*8);
                    cq = __builtin_amdgcn_mfma_f32_16x16x32_f16(af, bq, cq, 0, 0, 0);
                }
                #pragma unroll
                for (int e = 0; e < 4; ++e)
                    ql[(qb + lg*4 + e) * QLS + nt*16 + lr] = (f16)cq[e];
            }
        }
    }
    __syncthreads();   // kl/vt/ql ready (the kernel's only barrier)

    const int mA = wv * 32;

    // Q B-fragments for this wave's two q-tiles (constant across chunks: hoisted)
    const f16x8 bq0 = *(const f16x8*)(ql + (mA + lr) * QLS + lg * 8);
    const f16x8 bq1 = *(const f16x8*)(ql + (mA + 16 + lr) * QLS + lg * 8);

    f32x4 oc00 = {0.f,0.f,0.f,0.f}, oc01 = {0.f,0.f,0.f,0.f};
    f32x4 oc10 = {0.f,0.f,0.f,0.f}, oc11 = {0.f,0.f,0.f,0.f};
    float l0 = 0.f, l1 = 0.f;

    #pragma unroll 1
    for (int kk = 0; kk < 6; ++kk) {
        // S^T tiles: A = K rows (k as m), B = Q rows (q as n)
        const f16x8 ak0 = *(const f16x8*)(kl + (kk*32 + lr) * KS + lg * 8);
        const f16x8 ak1 = *(const f16x8*)(kl + (kk*32 + 16 + lr) * KS + lg * 8);
        const f32x4 ct00 = __builtin_amdgcn_mfma_f32_16x16x32_f16(ak0, bq0, (f32x4){0.f,0.f,0.f,0.f}, 0, 0, 0);
        const f32x4 ct01 = __builtin_amdgcn_mfma_f32_16x16x32_f16(ak0, bq1, (f32x4){0.f,0.f,0.f,0.f}, 0, 0, 0);
        const f32x4 ct10 = __builtin_amdgcn_mfma_f32_16x16x32_f16(ak1, bq0, (f32x4){0.f,0.f,0.f,0.f}, 0, 0, 0);
        const f32x4 ct11 = __builtin_amdgcn_mfma_f32_16x16x32_f16(ak1, bq1, (f32x4){0.f,0.f,0.f,0.f}, 0, 0, 0);

        // exp (P values; lane holds P[q=lr][k=kt*16+lg*4+e] per (kt,qt))
        float p00[4], p01[4], p10[4], p11[4];
        #pragma unroll
        for (int e = 0; e < 4; ++e) {
            p00[e] = exp2fast(fmaf(ct00[e], C1, CZN));
            p01[e] = exp2fast(fmaf(ct01[e], C1, CZN));
            p10[e] = exp2fast(fmaf(ct10[e], C1, CZN));
            p11[e] = exp2fast(fmaf(ct11[e], C1, CZN));
        }
        #pragma unroll
        for (int e = 0; e < 4; ++e) { l0 += p00[e] + p10[e]; l1 += p01[e] + p11[e]; }

        // pack kt0|kt1 pairs, then 8 shuffles build each P^T B-frag
        int pk0[4], pk1[4];
        #pragma unroll
        for (int e = 0; e < 4; ++e) {
            pk0[e] = f16x2_as_int(pk2(p00[e], p10[e]));
            pk1[e] = f16x2_as_int(pk2(p01[e], p11[e]));
        }
        f16x8 bp0, bp1;
        #pragma unroll
        for (int j = 0; j < 8; ++j) {
            const int sl = ((lg & 1) * 2 + (j >> 2)) * 16 + lr;
            const f16x2 v0 = int_as_f16x2(__shfl(pk0[j & 3], sl));
            const f16x2 v1 = int_as_f16x2(__shfl(pk1[j & 3], sl));
            bp0[j] = (lg < 2) ? v0.x : v0.y;
            bp1[j] = (lg < 2) ? v1.x : v1.y;
        }

        // PV (transposed): O^T tiles = mfma(V^T-frag, P^T-frag)
        const f16x8 av0 = *(const f16x8*)(vt + lr * VTS + kk*32 + lg*8);
        const f16x8 av1 = *(const f16x8*)(vt + (16 + lr) * VTS + kk*32 + lg*8);
        oc00 = __builtin_amdgcn_mfma_f32_16x16x32_f16(av0, bp0, oc00, 0, 0, 0);
        oc01 = __builtin_amdgcn_mfma_f32_16x16x32_f16(av0, bp1, oc01, 0, 0, 0);
        oc10 = __builtin_amdgcn_mfma_f32_16x16x32_f16(av1, bp0, oc10, 0, 0, 0);
        oc11 = __builtin_amdgcn_mfma_f32_16x16x32_f16(av1, bp1, oc11, 0, 0, 0);
    }

    // full row sums: reduce across lg lanes (same lr)
    l0 += __shfl_xor(l0, 16); l0 += __shfl_xor(l0, 32);
    l1 += __shfl_xor(l1, 16); l1 += __shfl_xor(l1, 32);

    // pz for q rows mA+lr (qt0) and mA+16+lr (qt1)
    float pz0, pz1;
    {
        const f16x2* qa = (const f16x2*)(ql + (mA + lr) * QLS);
        const f16x2* qb = (const f16x2*)(ql + (mA + 16 + lr) * QLS);
        float sa = 0.f, sb = 0.f;
        #pragma unroll
        for (int j = 0; j < 16; ++j) {
            const float w0 = bkv[cb + 2*j], w1 = bkv[cb + 2*j + 1];
            sa += (float)qa[j].x * w0 + (float)qa[j].y * w1;
            sb += (float)qb[j].x * w0 + (float)qb[j].y * w1;
        }
        pz0 = exp2fast(fmaf(sa, C1, CZV));
        pz1 = exp2fast(fmaf(sb, C1, CZV));
    }
    const float inv0 = 1.0f / (l0 + pz0), pzn0 = pz0 * inv0;
    const float inv1 = 1.0f / (l1 + pz1), pzn1 = pz1 * inv1;

    // epilogue: O^T tiles -> per-element store; lane's 4 values share one q row
    #define EPI_TILE(CC, MT, QT, INVQ, PZQ) { \
        const int q = mA + (QT) * 16 + lr; \
        const int v2 = q >> 6, tt2 = (q >> 4) & 3, nn2 = (q >> 2) & 3, dd2 = q & 3; \
        const size_t tk = ((size_t)(v2 * 8 + t * 4 + tt2) * 1024 + n * 4 + nn2) * 4 + dd2; \
        _Pragma("unroll") \
        for (int e = 0; e < 4; ++e) { \
            const int ch = (MT) * 16 + lg * 4 + e; \
            const float oo = fmaf(PZQ, bkv[128 + cb + ch], CC[e] * (INVQ)); \
            o_out[tk * 128 + cb + ch] = (f16)oo; \
        } }
    EPI_TILE(oc00, 0, 0, inv0, pzn0)
    EPI_TILE(oc01, 0, 1, inv1, pzn1)
    EPI_TILE(oc10, 1, 0, inv0, pzn0)
    EPI_TILE(oc11, 1, 1, inv1, pzn1)
    #undef EPI_TILE
}

// ---------------- Kernel 2: MFMA epilogue, 64 tokens/block (unchanged) ----------------
__global__ __launch_bounds__(256, 3) void k_epi(
    const float* __restrict__ x, const f16* __restrict__ o_in,
    const float* __restrict__ bo, const float* __restrict__ gamma,
    const float* __restrict__ ln2_s, const float* __restrict__ ln2_b,
    const float* __restrict__ b1, const float* __restrict__ b2,
    const float* __restrict__ gm, float* __restrict__ out)
{
    __shared__ __align__(16) char smem[EPI_LDS];
    f16* eol    = (f16*)(smem + OFF_EOL);
    float* etv  = (float*)(smem + OFF_ETV);
    f16* eh2    = (f16*)(smem + OFF_EH2);
    float* erd  = (float*)(smem + OFF_ERD);
    f16* ehid   = eol;

    const f16* WoF = (const f16*)(g_wpack + OFF_WO);
    const f16* W1F = (const f16*)(g_wpack + OFF_W1);
    const f16* W2F = (const f16*)(g_wpack + OFF_W2);

    const int tid = threadIdx.x;
    const int lane = tid & 63, wv = tid >> 6;
    const int lr = lane & 15, lg = lane >> 4;
    const int mb = wv * 16;
    const size_t tok0 = (size_t)blockIdx.x * 64;

    {
        const int tk = tid >> 2, part = tid & 3;
        const f16x8* src = (const f16x8*)(o_in + (tok0 + tk) * 128 + part * 32);
        f16x8* dst = (f16x8*)(eol + tk * EOLS + part * 32);
        dst[0] = src[0]; dst[1] = src[1]; dst[2] = src[2]; dst[3] = src[3];
    }
    __syncthreads();

    {
        f16x8 a_[4];
        #pragma unroll
        for (int ks = 0; ks < 4; ++ks)
            a_[ks] = *(const f16x8*)(eol + (mb + lr) * EOLS + ks*32 + lg*8);
        #pragma unroll
        for (int nt = 0; nt < 4; ++nt) {
            const int ch = nt * 16 + lr;
            f32x4 c = {0.f,0.f,0.f,0.f};
            c = __builtin_amdgcn_mfma_f32_16x16x32_f16(a_[0], *(const f16x8*)(WoF + ch*128 +  0 + lg*8), c, 0, 0, 0);
            c = __builtin_amdgcn_mfma_f32_16x16x32_f16(a_[1], *(const f16x8*)(WoF + ch*128 + 32 + lg*8), c, 0, 0, 0);
            c = __builtin_amdgcn_mfma_f32_16x16x32_f16(a_[2], *(const f16x8*)(WoF + ch*128 + 64 + lg*8), c, 0, 0, 0);
            c = __builtin_amdgcn_mfma_f32_16x16x32_f16(a_[3], *(const f16x8*)(WoF + ch*128 + 96 + lg*8), c, 0, 0, 0);
            const float bo_c = bo[ch], ga_c = gamma[ch];
            #pragma unroll
            for (int e = 0; e < 4; ++e) {
                const int tk = mb + lg*4 + e;
                etv[tk * ETVS + ch] = x[(tok0 + tk)*64 + ch] + ga_c * (c[e] + bo_c);
            }
        }
    }
    __syncthreads();

    {
        const int tk = tid >> 2, q = tid & 3;
        const float* tr = etv + tk * ETVS + q * 16;
        float s1 = 0.f, s2 = 0.f;
        #pragma unroll
        for (int j = 0; j < 16; ++j) { const float v = tr[j]; s1 += v; s2 += v*v; }
        erd[(tk*4 + q)*2] = s1; erd[(tk*4 + q)*2 + 1] = s2;
    }
    __syncthreads();
    {
        const int tk = tid >> 2, q = tid & 3;
        float a1 = 0.f, a2 = 0.f;
        #pragma unroll
        for (int i = 0; i < 4; ++i) { a1 += erd[(tk*4 + i)*2]; a2 += erd[(tk*4 + i)*2 + 1]; }
        const float mean = a1 * 0.015625f;
        const float rstd = rsqrtf(a2 * 0.015625f - mean*mean + 1e-5f);
        const float* tr = etv + tk * ETVS + q * 16;
        f16* hr = eh2 + tk * EH2S + q * 16;
        #pragma unroll
        for (int j = 0; j < 16; ++j)
            hr[j] = (f16)((tr[j]-mean)*rstd*ln2_s[q*16 + j] + ln2_b[q*16 + j]);
    }
    __syncthreads();

    {
        f16x8 a_[2];
        #pragma unroll
        for (int ks = 0; ks < 2; ++ks)
            a_[ks] = *(const f16x8*)(eh2 + (mb + lr) * EH2S + ks*32 + lg*8);
        #pragma unroll
        for (int nt = 0; nt < 8; ++nt) {
            const int ch = nt * 16 + lr;
            f32x4 c = {0.f,0.f,0.f,0.f};
            c = __builtin_amdgcn_mfma_f32_16x16x32_f16(a_[0], *(const f16x8*)(W1F + ch*64 +  0 + lg*8), c, 0, 0, 0);
            c = __builtin_amdgcn_mfma_f32_16x16x32_f16(a_[1], *(const f16x8*)(W1F + ch*64 + 32 + lg*8), c, 0, 0, 0);
            const float b1_c = b1[ch];
            #pragma unroll
            for (int e = 0; e < 4; ++e) {
                const int tk = mb + lg*4 + e;
                const float z = c[e] + b1_c;
                const float u = 0.7978845608028654f * (z + 0.044715f * z*z*z);
                ehid[tk * EOLS + ch] = (f16)(z / (1.0f + exp2fast(-2.8853900817779268f * u)));
            }
        }
    }
    __syncthreads();

    {
        f16x8 a_[4];
        #pragma unroll
        for (int ks = 0; ks < 4; ++ks)
            a_[ks] = *(const f16x8*)(ehid + (mb + lr) * EOLS + ks*32 + lg*8);
        #pragma unroll
        for (int nt = 0; nt < 4; ++nt) {
            const int ch = nt * 16 + lr;
            f32x4 c = {0.f,0.f,0.f,0.f};
            c = __builtin_amdgcn_mfma_f32_16x16x32_f16(a_[0], *(const f16x8*)(W2F + ch*128 +  0 + lg*8), c, 0, 0, 0);
            c = __builtin_amdgcn_mfma_f32_16x16x32_f16(a_[1], *(const f16x8*)(W2F + ch*128 + 32 + lg*8), c, 0, 0, 0);
            c = __builtin_amdgcn_mfma_f32_16x16x32_f16(a_[2], *(const f16x8*)(W2F + ch*128 + 64 + lg*8), c, 0, 0, 0);
            c = __builtin_amdgcn_mfma_f32_16x16x32_f16(a_[3], *(const f16x8*)(W2F + ch*128 + 96 + lg*8), c, 0, 0, 0);
            const float b2_c = b2[ch], gm_c = gm[ch];
            #pragma unroll
            for (int e = 0; e < 4; ++e) {
                const int tk = mb + lg*4 + e;
                out[(tok0 + tk)*64 + ch] = etv[tk * ETVS + ch] + gm_c * (c[e] + b2_c);
            }
        }
    }
}

extern "C" void kernel_launch(void* const* d_in, const int* in_sizes, int n_in,
                              void* d_out, int out_size, void* d_ws, size_t ws_size,
                              hipStream_t stream) {
    const float* x        = (const float*)d_in[0];
    const float* ln1_s    = (const float*)d_in[1];
    const float* ln1_b    = (const float*)d_in[2];
    const float* Wq       = (const float*)d_in[3];
    const float* Wkv      = (const float*)d_in[4];
    const float* bkv      = (const float*)d_in[5];
    const float* Wo       = (const float*)d_in[6];
    const float* bo       = (const float*)d_in[7];
    const float* gamma    = (const float*)d_in[8];
    const float* ln2_s    = (const float*)d_in[9];
    const float* ln2_b    = (const float*)d_in[10];
    const float* W1       = (const float*)d_in[11];
    const float* b1       = (const float*)d_in[12];
    const float* W2       = (const float*)d_in[13];
    const float* b2       = (const float*)d_in[14];
    const float* gamma_mlp= (const float*)d_in[15];

    // o (f16[65536][128]) aliases d_out (f32[65536][64]); disjoint token partition
    // between k_att writes and k_epi reads/overwrites -> race-free.
    f16* o_buf = (f16*)d_out;
    float* out = (float*)d_out;

    hipLaunchKernelGGL(k_conv, dim3(NPAIRS / 256), dim3(256), 0, stream,
                       Wq, Wkv, Wo, W1, W2);
    hipLaunchKernelGGL(k_ln, dim3(1024), dim3(256), 0, stream,
                       x, ln1_s, ln1_b);
    hipLaunchKernelGGL(k_att, dim3(2048), dim3(256), 0, stream,
                       bkv, o_buf);
    hipLaunchKernelGGL(k_epi, dim3(1024), dim3(256), 0, stream,
                       x, o_buf, bo, gamma, ln2_s, ln2_b, b1, b2, gamma_mlp, out);
}

// Round 23
// 80.402 us; speedup vs baseline: 1.1155x; 1.0725x over previous
//
#include <hip/hip_runtime.h>
#include <math.h>

typedef _Float16 f16;
typedef _Float16 f16x2 __attribute__((ext_vector_type(2)));
typedef _Float16 f16x4 __attribute__((ext_vector_type(4)));
typedef _Float16 f16x8 __attribute__((ext_vector_type(8)));
typedef float f32x4 __attribute__((ext_vector_type(4)));

#if defined(__has_builtin)
#if __has_builtin(__builtin_amdgcn_fdot2)
#define USE_FDOT2 1
#endif
#if __has_builtin(__builtin_amdgcn_exp2f)
#define USE_EXP2 1
#endif
#if __has_builtin(__builtin_amdgcn_cvt_pkrtz)
#define USE_PKRTZ 1
#endif
#endif

__device__ __forceinline__ float fdot2f(f16x2 a, f16x2 b, float c) {
#ifdef USE_FDOT2
    return __builtin_amdgcn_fdot2(a, b, c, false);
#else
    return c + (float)a.x * (float)b.x + (float)a.y * (float)b.y;
#endif
}
__device__ __forceinline__ float exp2fast(float a) {
#ifdef USE_EXP2
    return __builtin_amdgcn_exp2f(a);
#else
    return exp2f(a);
#endif
}
__device__ __forceinline__ f16x2 pk2(float a, float b) {
#ifdef USE_PKRTZ
    auto r0 = __builtin_amdgcn_cvt_pkrtz(a, b);
    f16x2 r; __builtin_memcpy(&r, &r0, 4); return r;
#else
    return (f16x2){(f16)a, (f16)b};
#endif
}
__device__ __forceinline__ int f16x2_as_int(f16x2 v) { int r; __builtin_memcpy(&r, &v, 4); return r; }
__device__ __forceinline__ f16x2 int_as_f16x2(int v) { f16x2 r; __builtin_memcpy(&r, &v, 4); return r; }

namespace {
// ---- k_att constants ----
constexpr int KS  = 40;
constexpr int QLS = 40;
constexpr int VTS = 200;
constexpr int OFF_KL = 0;            // 192*40*2 = 15360
constexpr int OFF_VT = 15360;        // 12800 -> 28160
constexpr int OFF_QL = 28160;        // 10240 -> 38400
constexpr int ATT_LDS = 38400;       // x4 = 153600 <= 160K -> 4 blocks/CU
constexpr float C1  = 0.2550600f;
constexpr float CZN = -5.7707801f;
constexpr float CZV = 2.5511480f;

// ---- packed-f16 weights: P[out][in/2] f16x2 pairs; row o = W[:,o] = B-fragment row o
constexpr int OFF_WQ  = 0;
constexpr int OFF_WKV = 4096;
constexpr int OFF_WO  = 12288;
constexpr int OFF_W1  = 16384;
constexpr int OFF_W2  = 20480;
constexpr int NPAIRS  = 24576;

// ---- k_epi constants (unchanged) ----
constexpr int EOLS = 136;
constexpr int ETVS = 66;
constexpr int EH2S = 72;
constexpr int OFF_EOL = 0;
constexpr int OFF_ETV = 17408;
constexpr int OFF_EH2 = 34304;
constexpr int OFF_ERD = 43520;
constexpr int EPI_LDS = 45568;
}

__device__ f16x2 g_wpack[NPAIRS];
// r23: g_h in MFMA A-FRAGMENT layout: [tokblk(4096)][ks(2)][lg(4)][lr(16)][j(8)] f16.
// Lane (lg*16+lr) reads offset (lg*16+lr)*16B -> one coalesced 1KB request per
// wave-load (was 16 cache lines per 16-lane group at token-row stride 128B).
__device__ f16 g_h[65536 * 64];

__device__ __forceinline__ const f16x8* hfrag(size_t tokblk, int ks, int lg, int lr) {
    return (const f16x8*)(g_h + (((tokblk * 2 + ks) * 4 + lg) * 16 + lr) * 8);
}

// ---------------- Kernel 0: pack GEMV weights to f16x2 ----------------
__global__ void k_conv(const float* __restrict__ Wq, const float* __restrict__ Wkv,
                       const float* __restrict__ Wo, const float* __restrict__ W1,
                       const float* __restrict__ W2) {
    const int i = blockIdx.x * 256 + threadIdx.x;
    const float* src; int inp, out, base;
    if (i < OFF_WKV)     { src = Wq;  inp = 32; out = 128; base = OFF_WQ;  }
    else if (i < OFF_WO) { src = Wkv; inp = 32; out = 256; base = OFF_WKV; }
    else if (i < OFF_W1) { src = Wo;  inp = 64; out = 64;  base = OFF_WO;  }
    else if (i < OFF_W2) { src = W1;  inp = 32; out = 128; base = OFF_W1;  }
    else                 { src = W2;  inp = 64; out = 64;  base = OFF_W2;  }
    const int li = i - base;
    const int o = li / inp, p = li % inp;
    g_wpack[i] = (f16x2){(f16)src[(2*p) * out + o], (f16)src[(2*p+1) * out + o]};
}

// ---------------- Kernel 0b: LN1 -> g_h (fragment layout). zero-LDS, 4 thr/token ------
__global__ __launch_bounds__(256, 8) void k_ln(
    const float* __restrict__ x,
    const float* __restrict__ ln1_s, const float* __restrict__ ln1_b) {
    const int tid = threadIdx.x;
    const size_t tok = (size_t)blockIdx.x * 64 + (tid >> 2);
    const int q = tid & 3;
    const float* xr = x + tok * 64 + q * 16;
    float v[16];
    {
        const float4 a = ((const float4*)xr)[0], b = ((const float4*)xr)[1];
        const float4 c = ((const float4*)xr)[2], d = ((const float4*)xr)[3];
        v[0]=a.x; v[1]=a.y; v[2]=a.z; v[3]=a.w;  v[4]=b.x; v[5]=b.y; v[6]=b.z; v[7]=b.w;
        v[8]=c.x; v[9]=c.y; v[10]=c.z; v[11]=c.w; v[12]=d.x; v[13]=d.y; v[14]=d.z; v[15]=d.w;
    }
    float s = 0.f, ss = 0.f;
    #pragma unroll
    for (int j = 0; j < 16; ++j) { s += v[j]; ss += v[j]*v[j]; }
    s  += __shfl_xor(s, 1);  s  += __shfl_xor(s, 2);
    ss += __shfl_xor(ss, 1); ss += __shfl_xor(ss, 2);
    const float mean = s * 0.015625f;
    const float rstd = rsqrtf(ss * 0.015625f - mean*mean + 1e-5f);
    f16x8 p0, p1;
    #pragma unroll
    for (int j = 0; j < 8; ++j) {
        p0[j] = (f16)((v[j]     - mean) * rstd * ln1_s[q*16 + j]     + ln1_b[q*16 + j]);
        p1[j] = (f16)((v[j + 8] - mean) * rstd * ln1_s[q*16 + j + 8] + ln1_b[q*16 + j + 8]);
    }
    // fragment layout: this thread owns (ks=q>>1, lg=(q&1)*2) and (.., lg+1), lr=tok&15
    const size_t tokblk = tok >> 4;
    const int lr = (int)(tok & 15);
    const int ks = q >> 1, lg0 = (q & 1) * 2;
    *(f16x8*)(g_h + (((tokblk * 2 + ks) * 4 + lg0) * 16 + lr) * 8)     = p0;
    *(f16x8*)(g_h + (((tokblk * 2 + ks) * 4 + lg0 + 1) * 16 + lr) * 8) = p1;
}

// ---------------- Kernel 1: per-(window,head) attention; P in registers ----------------
__global__ __launch_bounds__(256, 4) void k_att(
    const float* __restrict__ bkv,
    f16* __restrict__ o_out)
{
    __shared__ __align__(16) char smem[ATT_LDS];
    f16* kl   = (f16*)(smem + OFF_KL);
    f16* vt   = (f16*)(smem + OFF_VT);
    f16* ql   = (f16*)(smem + OFF_QL);

    const int tid  = threadIdx.x;
    const int bid  = blockIdx.x;
    const int w    = bid & 511;
    const int head = bid >> 9;
    const int cb   = head * 32;
    const int n    = w & 255;
    const int t    = w >> 8;

    const int lane = tid & 63, wv = tid >> 6;
    const int lr = lane & 15, lg = lane >> 4;

    const f16* WqF  = (const f16*)(g_wpack + OFF_WQ);
    const f16* WkvF = (const f16*)(g_wpack + OFF_WKV);

    // Phase C: MFMA projections; A-fragments from g_h (fragment layout, coalesced)
    {
        #pragma unroll
        for (int mi = 0; mi < 3; ++mi) {
            const int seg = wv * 3 + mi;                    // 0..11
            const int v_ = seg / 6;
            const int t2 = (seg % 6) + ((t == 0) ? 2 : 0);
            int tsrc, tt;
            if (t2 < 2)      { tsrc = t - 1; tt = t2 + 2; }
            else if (t2 < 6) { tsrc = t;     tt = t2 - 2; }
            else             { tsrc = t + 1; tt = t2 - 6; }
            const size_t tokblk = (size_t)(v_ * 8 + tsrc * 4 + tt) * 256 + n;
            const int mb = seg * 16;
            #pragma unroll
            for (int nt = 0; nt < 2; ++nt) {
                f32x4 ck = {0.f,0.f,0.f,0.f}, cv = {0.f,0.f,0.f,0.f};
                #pragma unroll
                for (int ks = 0; ks < 2; ++ks) {
                    const f16x8 af = *hfrag(tokblk, ks, lg, lr);
                    const f16x8 bk = *(const f16x8*)(WkvF + (cb + nt*16 + lr)*64 + ks*32 + lg*8);
                    const f16x8 bv = *(const f16x8*)(WkvF + (128 + cb + nt*16 + lr)*64 + ks*32 + lg*8);
                    ck = __builtin_amdgcn_mfma_f32_16x16x32_f16(af, bk, ck, 0, 0, 0);
                    cv = __builtin_amdgcn_mfma_f32_16x16x32_f16(af, bv, cv, 0, 0, 0);
                }
                const float bk_b = bkv[cb + nt*16 + lr];
                const float bv_b = bkv[128 + cb + nt*16 + lr];
                #pragma unroll
                for (int e = 0; e < 4; ++e) {
                    const int row = mb + lg*4 + e;
                    kl[row * KS + nt*16 + lr] = (f16)(ck[e] + bk_b);
                    vt[(nt*16 + lr) * VTS + row] = (f16)(cv[e] + bv_b);
                }
            }
        }
        #pragma unroll
        for (int mi = 0; mi < 2; ++mi) {
            const int qm = wv * 2 + mi;                     // 0..7
            const int v_ = qm >> 2, tt = qm & 3;
            const size_t tokblk = (size_t)(v_ * 8 + t * 4 + tt) * 256 + n;
            const int qb = v_ * 64 + tt * 16;
            #pragma unroll
            for (int nt = 0; nt < 2; ++nt) {
                f32x4 cq = {0.f,0.f,0.f,0.f};
                #pragma unroll
                for (int ks = 0; ks < 2; ++ks) {
                    const f16x8 af = *hfrag(tokblk, ks, lg, lr);
                    const f16x8 bq = *(const f16x8*)(WqF + (cb + nt*16 + lr)*64 + ks*32 + lg*8);
                    cq = __builtin_amdgcn_mfma_f32_16x16x32_f16(af, bq, cq, 0, 0, 0);
                }
                #pragma unroll
                for (int e = 0; e < 4; ++e)
                    ql[(qb + lg*4 + e) * QLS + nt*16 + lr] = (f16)cq[e];
            }
        }
    }
    __syncthreads();   // kl/vt/ql ready (the kernel's only barrier)

    const int mA = wv * 32;

    // Q B-fragments for this wave's two q-tiles (constant across chunks: hoisted)
    const f16x8 bq0 = *(const f16x8*)(ql + (mA + lr) * QLS + lg * 8);
    const f16x8 bq1 = *(const f16x8*)(ql + (mA + 16 + lr) * QLS + lg * 8);

    f32x4 oc00 = {0.f,0.f,0.f,0.f}, oc01 = {0.f,0.f,0.f,0.f};
    f32x4 oc10 = {0.f,0.f,0.f,0.f}, oc11 = {0.f,0.f,0.f,0.f};
    float l0 = 0.f, l1 = 0.f;

    #pragma unroll 1
    for (int kk = 0; kk < 6; ++kk) {
        // S^T tiles: A = K rows (k as m), B = Q rows (q as n)
        const f16x8 ak0 = *(const f16x8*)(kl + (kk*32 + lr) * KS + lg * 8);
        const f16x8 ak1 = *(const f16x8*)(kl + (kk*32 + 16 + lr) * KS + lg * 8);
        const f32x4 ct00 = __builtin_amdgcn_mfma_f32_16x16x32_f16(ak0, bq0, (f32x4){0.f,0.f,0.f,0.f}, 0, 0, 0);
        const f32x4 ct01 = __builtin_amdgcn_mfma_f32_16x16x32_f16(ak0, bq1, (f32x4){0.f,0.f,0.f,0.f}, 0, 0, 0);
        const f32x4 ct10 = __builtin_amdgcn_mfma_f32_16x16x32_f16(ak1, bq0, (f32x4){0.f,0.f,0.f,0.f}, 0, 0, 0);
        const f32x4 ct11 = __builtin_amdgcn_mfma_f32_16x16x32_f16(ak1, bq1, (f32x4){0.f,0.f,0.f,0.f}, 0, 0, 0);

        float p00[4], p01[4], p10[4], p11[4];
        #pragma unroll
        for (int e = 0; e < 4; ++e) {
            p00[e] = exp2fast(fmaf(ct00[e], C1, CZN));
            p01[e] = exp2fast(fmaf(ct01[e], C1, CZN));
            p10[e] = exp2fast(fmaf(ct10[e], C1, CZN));
            p11[e] = exp2fast(fmaf(ct11[e], C1, CZN));
        }
        #pragma unroll
        for (int e = 0; e < 4; ++e) { l0 += p00[e] + p10[e]; l1 += p01[e] + p11[e]; }

        int pk0[4], pk1[4];
        #pragma unroll
        for (int e = 0; e < 4; ++e) {
            pk0[e] = f16x2_as_int(pk2(p00[e], p10[e]));
            pk1[e] = f16x2_as_int(pk2(p01[e], p11[e]));
        }
        f16x8 bp0, bp1;
        #pragma unroll
        for (int j = 0; j < 8; ++j) {
            const int sl = ((lg & 1) * 2 + (j >> 2)) * 16 + lr;
            const f16x2 v0 = int_as_f16x2(__shfl(pk0[j & 3], sl));
            const f16x2 v1 = int_as_f16x2(__shfl(pk1[j & 3], sl));
            bp0[j] = (lg < 2) ? v0.x : v0.y;
            bp1[j] = (lg < 2) ? v1.x : v1.y;
        }

        const f16x8 av0 = *(const f16x8*)(vt + lr * VTS + kk*32 + lg*8);
        const f16x8 av1 = *(const f16x8*)(vt + (16 + lr) * VTS + kk*32 + lg*8);
        oc00 = __builtin_amdgcn_mfma_f32_16x16x32_f16(av0, bp0, oc00, 0, 0, 0);
        oc01 = __builtin_amdgcn_mfma_f32_16x16x32_f16(av0, bp1, oc01, 0, 0, 0);
        oc10 = __builtin_amdgcn_mfma_f32_16x16x32_f16(av1, bp0, oc10, 0, 0, 0);
        oc11 = __builtin_amdgcn_mfma_f32_16x16x32_f16(av1, bp1, oc11, 0, 0, 0);
    }

    l0 += __shfl_xor(l0, 16); l0 += __shfl_xor(l0, 32);
    l1 += __shfl_xor(l1, 16); l1 += __shfl_xor(l1, 32);

    float pz0, pz1;
    {
        const f16x2* qa = (const f16x2*)(ql + (mA + lr) * QLS);
        const f16x2* qb = (const f16x2*)(ql + (mA + 16 + lr) * QLS);
        float sa = 0.f, sb = 0.f;
        #pragma unroll
        for (int j = 0; j < 16; ++j) {
            const float w0 = bkv[cb + 2*j], w1 = bkv[cb + 2*j + 1];
            sa += (float)qa[j].x * w0 + (float)qa[j].y * w1;
            sb += (float)qb[j].x * w0 + (float)qb[j].y * w1;
        }
        pz0 = exp2fast(fmaf(sa, C1, CZV));
        pz1 = exp2fast(fmaf(sb, C1, CZV));
    }
    const float inv0 = 1.0f / (l0 + pz0), pzn0 = pz0 * inv0;
    const float inv1 = 1.0f / (l1 + pz1), pzn1 = pz1 * inv1;

    #define EPI_TILE(CC, MT, QT, INVQ, PZQ) { \
        const int q = mA + (QT) * 16 + lr; \
        const int v2 = q >> 6, tt2 = (q >> 4) & 3, nn2 = (q >> 2) & 3, dd2 = q & 3; \
        const size_t tk = ((size_t)(v2 * 8 + t * 4 + tt2) * 1024 + n * 4 + nn2) * 4 + dd2; \
        _Pragma("unroll") \
        for (int e = 0; e < 4; ++e) { \
            const int ch = (MT) * 16 + lg * 4 + e; \
            const float oo = fmaf(PZQ, bkv[128 + cb + ch], CC[e] * (INVQ)); \
            o_out[tk * 128 + cb + ch] = (f16)oo; \
        } }
    EPI_TILE(oc00, 0, 0, inv0, pzn0)
    EPI_TILE(oc01, 0, 1, inv1, pzn1)
    EPI_TILE(oc10, 1, 0, inv0, pzn0)
    EPI_TILE(oc11, 1, 1, inv1, pzn1)
    #undef EPI_TILE
}

// ---------------- Kernel 2: MFMA epilogue, 64 tokens/block (unchanged) ----------------
__global__ __launch_bounds__(256, 3) void k_epi(
    const float* __restrict__ x, const f16* __restrict__ o_in,
    const float* __restrict__ bo, const float* __restrict__ gamma,
    const float* __restrict__ ln2_s, const float* __restrict__ ln2_b,
    const float* __restrict__ b1, const float* __restrict__ b2,
    const float* __restrict__ gm, float* __restrict__ out)
{
    __shared__ __align__(16) char smem[EPI_LDS];
    f16* eol    = (f16*)(smem + OFF_EOL);
    float* etv  = (float*)(smem + OFF_ETV);
    f16* eh2    = (f16*)(smem + OFF_EH2);
    float* erd  = (float*)(smem + OFF_ERD);
    f16* ehid   = eol;

    const f16* WoF = (const f16*)(g_wpack + OFF_WO);
    const f16* W1F = (const f16*)(g_wpack + OFF_W1);
    const f16* W2F = (const f16*)(g_wpack + OFF_W2);

    const int tid = threadIdx.x;
    const int lane = tid & 63, wv = tid >> 6;
    const int lr = lane & 15, lg = lane >> 4;
    const int mb = wv * 16;
    const size_t tok0 = (size_t)blockIdx.x * 64;

    {
        const int tk = tid >> 2, part = tid & 3;
        const f16x8* src = (const f16x8*)(o_in + (tok0 + tk) * 128 + part * 32);
        f16x8* dst = (f16x8*)(eol + tk * EOLS + part * 32);
        dst[0] = src[0]; dst[1] = src[1]; dst[2] = src[2]; dst[3] = src[3];
    }
    __syncthreads();

    {
        f16x8 a_[4];
        #pragma unroll
        for (int ks = 0; ks < 4; ++ks)
            a_[ks] = *(const f16x8*)(eol + (mb + lr) * EOLS + ks*32 + lg*8);
        #pragma unroll
        for (int nt = 0; nt < 4; ++nt) {
            const int ch = nt * 16 + lr;
            f32x4 c = {0.f,0.f,0.f,0.f};
            c = __builtin_amdgcn_mfma_f32_16x16x32_f16(a_[0], *(const f16x8*)(WoF + ch*128 +  0 + lg*8), c, 0, 0, 0);
            c = __builtin_amdgcn_mfma_f32_16x16x32_f16(a_[1], *(const f16x8*)(WoF + ch*128 + 32 + lg*8), c, 0, 0, 0);
            c = __builtin_amdgcn_mfma_f32_16x16x32_f16(a_[2], *(const f16x8*)(WoF + ch*128 + 64 + lg*8), c, 0, 0, 0);
            c = __builtin_amdgcn_mfma_f32_16x16x32_f16(a_[3], *(const f16x8*)(WoF + ch*128 + 96 + lg*8), c, 0, 0, 0);
            const float bo_c = bo[ch], ga_c = gamma[ch];
            #pragma unroll
            for (int e = 0; e < 4; ++e) {
                const int tk = mb + lg*4 + e;
                etv[tk * ETVS + ch] = x[(tok0 + tk)*64 + ch] + ga_c * (c[e] + bo_c);
            }
        }
    }
    __syncthreads();

    {
        const int tk = tid >> 2, q = tid & 3;
        const float* tr = etv + tk * ETVS + q * 16;
        float s1 = 0.f, s2 = 0.f;
        #pragma unroll
        for (int j = 0; j < 16; ++j) { const float v = tr[j]; s1 += v; s2 += v*v; }
        erd[(tk*4 + q)*2] = s1; erd[(tk*4 + q)*2 + 1] = s2;
    }
    __syncthreads();
    {
        const int tk = tid >> 2, q = tid & 3;
        float a1 = 0.f, a2 = 0.f;
        #pragma unroll
        for (int i = 0; i < 4; ++i) { a1 += erd[(tk*4 + i)*2]; a2 += erd[(tk*4 + i)*2 + 1]; }
        const float mean = a1 * 0.015625f;
        const float rstd = rsqrtf(a2 * 0.015625f - mean*mean + 1e-5f);
        const float* tr = etv + tk * ETVS + q * 16;
        f16* hr = eh2 + tk * EH2S + q * 16;
        #pragma unroll
        for (int j = 0; j < 16; ++j)
            hr[j] = (f16)((tr[j]-mean)*rstd*ln2_s[q*16 + j] + ln2_b[q*16 + j]);
    }
    __syncthreads();

    {
        f16x8 a_[2];
        #pragma unroll
        for (int ks = 0; ks < 2; ++ks)
            a_[ks] = *(const f16x8*)(eh2 + (mb + lr) * EH2S + ks*32 + lg*8);
        #pragma unroll
        for (int nt = 0; nt < 8; ++nt) {
            const int ch = nt * 16 + lr;
            f32x4 c = {0.f,0.f,0.f,0.f};
            c = __builtin_amdgcn_mfma_f32_16x16x32_f16(a_[0], *(const f16x8*)(W1F + ch*64 +  0 + lg*8), c, 0, 0, 0);
            c = __builtin_amdgcn_mfma_f32_16x16x32_f16(a_[1], *(const f16x8*)(W1F + ch*64 + 32 + lg*8), c, 0, 0, 0);
            const float b1_c = b1[ch];
            #pragma unroll
            for (int e = 0; e < 4; ++e) {
                const int tk = mb + lg*4 + e;
                const float z = c[e] + b1_c;
                const float u = 0.7978845608028654f * (z + 0.044715f * z*z*z);
                ehid[tk * EOLS + ch] = (f16)(z / (1.0f + exp2fast(-2.8853900817779268f * u)));
            }
        }
    }
    __syncthreads();

    {
        f16x8 a_[4];
        #pragma unroll
        for (int ks = 0; ks < 4; ++ks)
            a_[ks] = *(const f16x8*)(ehid + (mb + lr) * EOLS + ks*32 + lg*8);
        #pragma unroll
        for (int nt = 0; nt < 4; ++nt) {
            const int ch = nt * 16 + lr;
            f32x4 c = {0.f,0.f,0.f,0.f};
            c = __builtin_amdgcn_mfma_f32_16x16x32_f16(a_[0], *(const f16x8*)(W2F + ch*128 +  0 + lg*8), c, 0, 0, 0);
            c = __builtin_amdgcn_mfma_f32_16x16x32_f16(a_[1], *(const f16x8*)(W2F + ch*128 + 32 + lg*8), c, 0, 0, 0);
            c = __builtin_amdgcn_mfma_f32_16x16x32_f16(a_[2], *(const f16x8*)(W2F + ch*128 + 64 + lg*8), c, 0, 0, 0);
            c = __builtin_amdgcn_mfma_f32_16x16x32_f16(a_[3], *(const f16x8*)(W2F + ch*128 + 96 + lg*8), c, 0, 0, 0);
            const float b2_c = b2[ch], gm_c = gm[ch];
            #pragma unroll
            for (int e = 0; e < 4; ++e) {
                const int tk = mb + lg*4 + e;
                out[(tok0 + tk)*64 + ch] = etv[tk * ETVS + ch] + gm_c * (c[e] + b2_c);
            }
        }
    }
}

extern "C" void kernel_launch(void* const* d_in, const int* in_sizes, int n_in,
                              void* d_out, int out_size, void* d_ws, size_t ws_size,
                              hipStream_t stream) {
    const float* x        = (const float*)d_in[0];
    const float* ln1_s    = (const float*)d_in[1];
    const float* ln1_b    = (const float*)d_in[2];
    const float* Wq       = (const float*)d_in[3];
    const float* Wkv      = (const float*)d_in[4];
    const float* bkv      = (const float*)d_in[5];
    const float* Wo       = (const float*)d_in[6];
    const float* bo       = (const float*)d_in[7];
    const float* gamma    = (const float*)d_in[8];
    const float* ln2_s    = (const float*)d_in[9];
    const float* ln2_b    = (const float*)d_in[10];
    const float* W1       = (const float*)d_in[11];
    const float* b1       = (const float*)d_in[12];
    const float* W2       = (const float*)d_in[13];
    const float* b2       = (const float*)d_in[14];
    const float* gamma_mlp= (const float*)d_in[15];

    // o (f16[65536][128]) aliases d_out (f32[65536][64]); disjoint token partition
    // between k_att writes and k_epi reads/overwrites -> race-free.
    f16* o_buf = (f16*)d_out;
    float* out = (float*)d_out;

    hipLaunchKernelGGL(k_conv, dim3(NPAIRS / 256), dim3(256), 0, stream,
                       Wq, Wkv, Wo, W1, W2);
    hipLaunchKernelGGL(k_ln, dim3(1024), dim3(256), 0, stream,
                       x, ln1_s, ln1_b);
    hipLaunchKernelGGL(k_att, dim3(2048), dim3(256), 0, stream,
                       bkv, o_buf);
    hipLaunchKernelGGL(k_epi, dim3(1024), dim3(256), 0, stream,
                       x, o_buf, bo, gamma, ln2_s, ln2_b, b1, b2, gamma_mlp, out);
}

// Round 24
// 59.462 us; speedup vs baseline: 1.5084x; 1.3522x over previous
//
#include <hip/hip_runtime.h>
#include <math.h>

typedef _Float16 f16;
typedef _Float16 f16x2 __attribute__((ext_vector_type(2)));
typedef _Float16 f16x4 __attribute__((ext_vector_type(4)));
typedef _Float16 f16x8 __attribute__((ext_vector_type(8)));
typedef float f32x4 __attribute__((ext_vector_type(4)));

#if defined(__has_builtin)
#if __has_builtin(__builtin_amdgcn_fdot2)
#define USE_FDOT2 1
#endif
#if __has_builtin(__builtin_amdgcn_exp2f)
#define USE_EXP2 1
#endif
#if __has_builtin(__builtin_amdgcn_cvt_pkrtz)
#define USE_PKRTZ 1
#endif
#endif

__device__ __forceinline__ float fdot2f(f16x2 a, f16x2 b, float c) {
#ifdef USE_FDOT2
    return __builtin_amdgcn_fdot2(a, b, c, false);
#else
    return c + (float)a.x * (float)b.x + (float)a.y * (float)b.y;
#endif
}
__device__ __forceinline__ float exp2fast(float a) {
#ifdef USE_EXP2
    return __builtin_amdgcn_exp2f(a);
#else
    return exp2f(a);
#endif
}
__device__ __forceinline__ f16x2 pk2(float a, float b) {
#ifdef USE_PKRTZ
    auto r0 = __builtin_amdgcn_cvt_pkrtz(a, b);
    f16x2 r; __builtin_memcpy(&r, &r0, 4); return r;
#else
    return (f16x2){(f16)a, (f16)b};
#endif
}
__device__ __forceinline__ int f16x2_as_int(f16x2 v) { int r; __builtin_memcpy(&r, &v, 4); return r; }
__device__ __forceinline__ f16x2 int_as_f16x2(int v) { f16x2 r; __builtin_memcpy(&r, &v, 4); return r; }

namespace {
// ---- k_att constants ----
constexpr int KS  = 40;
constexpr int QLS = 40;
constexpr int VTS = 200;
constexpr int OFF_KL = 0;            // 192*40*2 = 15360
constexpr int OFF_VT = 15360;        // 12800 -> 28160
constexpr int OFF_QL = 28160;        // 10240 -> 38400
constexpr int ATT_LDS = 38400;       // x4 = 153600 <= 160K -> 4 blocks/CU
constexpr float C1  = 0.2550600f;
constexpr float CZN = -5.7707801f;
constexpr float CZV = 2.5511480f;

// ---- r24: weights in MFMA B-FRAGMENT layout [ot][ks][lg][lr][j] f16.
// Lane (lg*16+lr) reads offset lane*16B -> coalesced 1KB wave-load (was
// 16 cache lines / 16-lane group at 128B row stride).
constexpr int FR_WQ  = 0;        // IN=64  OUT=128 -> 8192
constexpr int FR_WKV = 8192;     // IN=64  OUT=256 -> 16384
constexpr int FR_WO  = 24576;    // IN=128 OUT=64  -> 8192
constexpr int FR_W1  = 32768;    // IN=64  OUT=128 -> 8192
constexpr int FR_W2  = 40960;    // IN=128 OUT=64  -> 8192
constexpr int NWF    = 49152;    // total f16 (96 KB)

// ---- k_epi constants (unchanged) ----
constexpr int EOLS = 136;
constexpr int ETVS = 66;
constexpr int EH2S = 72;
constexpr int OFF_EOL = 0;
constexpr int OFF_ETV = 17408;
constexpr int OFF_EH2 = 34304;
constexpr int OFF_ERD = 43520;
constexpr int EPI_LDS = 45568;
}

__device__ f16 g_wfrag[NWF];
// g_h in MFMA A-FRAGMENT layout: [tokblk(4096)][ks(2)][lg(4)][lr(16)][j(8)] f16.
__device__ f16 g_h[65536 * 64];

__device__ __forceinline__ const f16x8* hfrag(size_t tokblk, int ks, int lg, int lr) {
    return (const f16x8*)(g_h + (((tokblk * 2 + ks) * 4 + lg) * 16 + lr) * 8);
}
__device__ __forceinline__ const f16x8* wfrag(int base, int nks, int ot, int ks, int lg, int lr) {
    return (const f16x8*)(g_wfrag + base + (((ot * nks + ks) * 4 + lg) * 16 + lr) * 8);
}

// ---------------- Kernel 0: weights -> fragment-layout f16 ----------------
__global__ void k_conv(const float* __restrict__ Wq, const float* __restrict__ Wkv,
                       const float* __restrict__ Wo, const float* __restrict__ W1,
                       const float* __restrict__ W2) {
    const int i = blockIdx.x * 256 + threadIdx.x;      // f16 element index
    const float* src; int IN, OUT, base;
    if (i < FR_WKV)      { src = Wq;  IN = 64;  OUT = 128; base = FR_WQ;  }
    else if (i < FR_WO)  { src = Wkv; IN = 64;  OUT = 256; base = FR_WKV; }
    else if (i < FR_W1)  { src = Wo;  IN = 128; OUT = 64;  base = FR_WO;  }
    else if (i < FR_W2)  { src = W1;  IN = 64;  OUT = 128; base = FR_W1;  }
    else                 { src = W2;  IN = 128; OUT = 64;  base = FR_W2;  }
    const int local = i - base;
    const int j  = local & 7;
    const int lr = (local >> 3) & 15;
    const int lg = (local >> 7) & 3;
    const int nks = IN >> 5;                            // 2 or 4 (power of 2)
    const int ks = (local >> 9) & (nks - 1);
    const int ot = local >> (9 + ((nks == 2) ? 1 : 2));
    const int in  = ks * 32 + lg * 8 + j;
    const int out = ot * 16 + lr;
    g_wfrag[i] = (f16)src[in * OUT + out];
}

// ---------------- Kernel 0b: LN1 -> g_h (fragment layout). zero-LDS, 4 thr/token ------
__global__ __launch_bounds__(256, 8) void k_ln(
    const float* __restrict__ x,
    const float* __restrict__ ln1_s, const float* __restrict__ ln1_b) {
    const int tid = threadIdx.x;
    const size_t tok = (size_t)blockIdx.x * 64 + (tid >> 2);
    const int q = tid & 3;
    const float* xr = x + tok * 64 + q * 16;
    float v[16];
    {
        const float4 a = ((const float4*)xr)[0], b = ((const float4*)xr)[1];
        const float4 c = ((const float4*)xr)[2], d = ((const float4*)xr)[3];
        v[0]=a.x; v[1]=a.y; v[2]=a.z; v[3]=a.w;  v[4]=b.x; v[5]=b.y; v[6]=b.z; v[7]=b.w;
        v[8]=c.x; v[9]=c.y; v[10]=c.z; v[11]=c.w; v[12]=d.x; v[13]=d.y; v[14]=d.z; v[15]=d.w;
    }
    float s = 0.f, ss = 0.f;
    #pragma unroll
    for (int j = 0; j < 16; ++j) { s += v[j]; ss += v[j]*v[j]; }
    s  += __shfl_xor(s, 1);  s  += __shfl_xor(s, 2);
    ss += __shfl_xor(ss, 1); ss += __shfl_xor(ss, 2);
    const float mean = s * 0.015625f;
    const float rstd = rsqrtf(ss * 0.015625f - mean*mean + 1e-5f);
    f16x8 p0, p1;
    #pragma unroll
    for (int j = 0; j < 8; ++j) {
        p0[j] = (f16)((v[j]     - mean) * rstd * ln1_s[q*16 + j]     + ln1_b[q*16 + j]);
        p1[j] = (f16)((v[j + 8] - mean) * rstd * ln1_s[q*16 + j + 8] + ln1_b[q*16 + j + 8]);
    }
    const size_t tokblk = tok >> 4;
    const int lr = (int)(tok & 15);
    const int ks = q >> 1, lg0 = (q & 1) * 2;
    *(f16x8*)(g_h + (((tokblk * 2 + ks) * 4 + lg0) * 16 + lr) * 8)     = p0;
    *(f16x8*)(g_h + (((tokblk * 2 + ks) * 4 + lg0 + 1) * 16 + lr) * 8) = p1;
}

// ---------------- Kernel 1: per-(window,head) attention; P in registers ----------------
__global__ __launch_bounds__(256, 4) void k_att(
    const float* __restrict__ bkv,
    f16* __restrict__ o_out)
{
    __shared__ __align__(16) char smem[ATT_LDS];
    f16* kl   = (f16*)(smem + OFF_KL);
    f16* vt   = (f16*)(smem + OFF_VT);
    f16* ql   = (f16*)(smem + OFF_QL);

    const int tid  = threadIdx.x;
    const int bid  = blockIdx.x;
    const int w    = bid & 511;
    const int head = bid >> 9;
    const int cb   = head * 32;
    const int n    = w & 255;
    const int t    = w >> 8;

    const int lane = tid & 63, wv = tid >> 6;
    const int lr = lane & 15, lg = lane >> 4;

    // Phase C: MFMA projections; A-frags from g_h, B-frags from g_wfrag (both coalesced)
    {
        #pragma unroll
        for (int mi = 0; mi < 3; ++mi) {
            const int seg = wv * 3 + mi;                    // 0..11
            const int v_ = seg / 6;
            const int t2 = (seg % 6) + ((t == 0) ? 2 : 0);
            int tsrc, tt;
            if (t2 < 2)      { tsrc = t - 1; tt = t2 + 2; }
            else if (t2 < 6) { tsrc = t;     tt = t2 - 2; }
            else             { tsrc = t + 1; tt = t2 - 6; }
            const size_t tokblk = (size_t)(v_ * 8 + tsrc * 4 + tt) * 256 + n;
            const int mb = seg * 16;
            #pragma unroll
            for (int nt = 0; nt < 2; ++nt) {
                f32x4 ck = {0.f,0.f,0.f,0.f}, cv = {0.f,0.f,0.f,0.f};
                #pragma unroll
                for (int ks = 0; ks < 2; ++ks) {
                    const f16x8 af = *hfrag(tokblk, ks, lg, lr);
                    const f16x8 bk = *wfrag(FR_WKV, 2, head*2 + nt, ks, lg, lr);
                    const f16x8 bv = *wfrag(FR_WKV, 2, 8 + head*2 + nt, ks, lg, lr);
                    ck = __builtin_amdgcn_mfma_f32_16x16x32_f16(af, bk, ck, 0, 0, 0);
                    cv = __builtin_amdgcn_mfma_f32_16x16x32_f16(af, bv, cv, 0, 0, 0);
                }
                const float bk_b = bkv[cb + nt*16 + lr];
                const float bv_b = bkv[128 + cb + nt*16 + lr];
                #pragma unroll
                for (int e = 0; e < 4; ++e) {
                    const int row = mb + lg*4 + e;
                    kl[row * KS + nt*16 + lr] = (f16)(ck[e] + bk_b);
                    vt[(nt*16 + lr) * VTS + row] = (f16)(cv[e] + bv_b);
                }
            }
        }
        #pragma unroll
        for (int mi = 0; mi < 2; ++mi) {
            const int qm = wv * 2 + mi;                     // 0..7
            const int v_ = qm >> 2, tt = qm & 3;
            const size_t tokblk = (size_t)(v_ * 8 + t * 4 + tt) * 256 + n;
            const int qb = v_ * 64 + tt * 16;
            #pragma unroll
            for (int nt = 0; nt < 2; ++nt) {
                f32x4 cq = {0.f,0.f,0.f,0.f};
                #pragma unroll
                for (int ks = 0; ks < 2; ++ks) {
                    const f16x8 af = *hfrag(tokblk, ks, lg, lr);
                    const f16x8 bq = *wfrag(FR_WQ, 2, head*2 + nt, ks, lg, lr);
                    cq = __builtin_amdgcn_mfma_f32_16x16x32_f16(af, bq, cq, 0, 0, 0);
                }
                #pragma unroll
                for (int e = 0; e < 4; ++e)
                    ql[(qb + lg*4 + e) * QLS + nt*16 + lr] = (f16)cq[e];
            }
        }
    }
    __syncthreads();   // kl/vt/ql ready (the kernel's only barrier)

    const int mA = wv * 32;

    const f16x8 bq0 = *(const f16x8*)(ql + (mA + lr) * QLS + lg * 8);
    const f16x8 bq1 = *(const f16x8*)(ql + (mA + 16 + lr) * QLS + lg * 8);

    f32x4 oc00 = {0.f,0.f,0.f,0.f}, oc01 = {0.f,0.f,0.f,0.f};
    f32x4 oc10 = {0.f,0.f,0.f,0.f}, oc11 = {0.f,0.f,0.f,0.f};
    float l0 = 0.f, l1 = 0.f;

    #pragma unroll 1
    for (int kk = 0; kk < 6; ++kk) {
        const f16x8 ak0 = *(const f16x8*)(kl + (kk*32 + lr) * KS + lg * 8);
        const f16x8 ak1 = *(const f16x8*)(kl + (kk*32 + 16 + lr) * KS + lg * 8);
        const f32x4 ct00 = __builtin_amdgcn_mfma_f32_16x16x32_f16(ak0, bq0, (f32x4){0.f,0.f,0.f,0.f}, 0, 0, 0);
        const f32x4 ct01 = __builtin_amdgcn_mfma_f32_16x16x32_f16(ak0, bq1, (f32x4){0.f,0.f,0.f,0.f}, 0, 0, 0);
        const f32x4 ct10 = __builtin_amdgcn_mfma_f32_16x16x32_f16(ak1, bq0, (f32x4){0.f,0.f,0.f,0.f}, 0, 0, 0);
        const f32x4 ct11 = __builtin_amdgcn_mfma_f32_16x16x32_f16(ak1, bq1, (f32x4){0.f,0.f,0.f,0.f}, 0, 0, 0);

        float p00[4], p01[4], p10[4], p11[4];
        #pragma unroll
        for (int e = 0; e < 4; ++e) {
            p00[e] = exp2fast(fmaf(ct00[e], C1, CZN));
            p01[e] = exp2fast(fmaf(ct01[e], C1, CZN));
            p10[e] = exp2fast(fmaf(ct10[e], C1, CZN));
            p11[e] = exp2fast(fmaf(ct11[e], C1, CZN));
        }
        #pragma unroll
        for (int e = 0; e < 4; ++e) { l0 += p00[e] + p10[e]; l1 += p01[e] + p11[e]; }

        int pk0[4], pk1[4];
        #pragma unroll
        for (int e = 0; e < 4; ++e) {
            pk0[e] = f16x2_as_int(pk2(p00[e], p10[e]));
            pk1[e] = f16x2_as_int(pk2(p01[e], p11[e]));
        }
        f16x8 bp0, bp1;
        #pragma unroll
        for (int j = 0; j < 8; ++j) {
            const int sl = ((lg & 1) * 2 + (j >> 2)) * 16 + lr;
            const f16x2 v0 = int_as_f16x2(__shfl(pk0[j & 3], sl));
            const f16x2 v1 = int_as_f16x2(__shfl(pk1[j & 3], sl));
            bp0[j] = (lg < 2) ? v0.x : v0.y;
            bp1[j] = (lg < 2) ? v1.x : v1.y;
        }

        const f16x8 av0 = *(const f16x8*)(vt + lr * VTS + kk*32 + lg*8);
        const f16x8 av1 = *(const f16x8*)(vt + (16 + lr) * VTS + kk*32 + lg*8);
        oc00 = __builtin_amdgcn_mfma_f32_16x16x32_f16(av0, bp0, oc00, 0, 0, 0);
        oc01 = __builtin_amdgcn_mfma_f32_16x16x32_f16(av0, bp1, oc01, 0, 0, 0);
        oc10 = __builtin_amdgcn_mfma_f32_16x16x32_f16(av1, bp0, oc10, 0, 0, 0);
        oc11 = __builtin_amdgcn_mfma_f32_16x16x32_f16(av1, bp1, oc11, 0, 0, 0);
    }

    l0 += __shfl_xor(l0, 16); l0 += __shfl_xor(l0, 32);
    l1 += __shfl_xor(l1, 16); l1 += __shfl_xor(l1, 32);

    float pz0, pz1;
    {
        const f16x2* qa = (const f16x2*)(ql + (mA + lr) * QLS);
        const f16x2* qb = (const f16x2*)(ql + (mA + 16 + lr) * QLS);
        float sa = 0.f, sb = 0.f;
        #pragma unroll
        for (int j = 0; j < 16; ++j) {
            const float w0 = bkv[cb + 2*j], w1 = bkv[cb + 2*j + 1];
            sa += (float)qa[j].x * w0 + (float)qa[j].y * w1;
            sb += (float)qb[j].x * w0 + (float)qb[j].y * w1;
        }
        pz0 = exp2fast(fmaf(sa, C1, CZV));
        pz1 = exp2fast(fmaf(sb, C1, CZV));
    }
    const float inv0 = 1.0f / (l0 + pz0), pzn0 = pz0 * inv0;
    const float inv1 = 1.0f / (l1 + pz1), pzn1 = pz1 * inv1;

    #define EPI_TILE(CC, MT, QT, INVQ, PZQ) { \
        const int q = mA + (QT) * 16 + lr; \
        const int v2 = q >> 6, tt2 = (q >> 4) & 3, nn2 = (q >> 2) & 3, dd2 = q & 3; \
        const size_t tk = ((size_t)(v2 * 8 + t * 4 + tt2) * 1024 + n * 4 + nn2) * 4 + dd2; \
        _Pragma("unroll") \
        for (int e = 0; e < 4; ++e) { \
            const int ch = (MT) * 16 + lg * 4 + e; \
            const float oo = fmaf(PZQ, bkv[128 + cb + ch], CC[e] * (INVQ)); \
            o_out[tk * 128 + cb + ch] = (f16)oo; \
        } }
    EPI_TILE(oc00, 0, 0, inv0, pzn0)
    EPI_TILE(oc01, 0, 1, inv1, pzn1)
    EPI_TILE(oc10, 1, 0, inv0, pzn0)
    EPI_TILE(oc11, 1, 1, inv1, pzn1)
    #undef EPI_TILE
}

// ---------------- Kernel 2: MFMA epilogue, 64 tokens/block ----------------
__global__ __launch_bounds__(256, 3) void k_epi(
    const float* __restrict__ x, const f16* __restrict__ o_in,
    const float* __restrict__ bo, const float* __restrict__ gamma,
    const float* __restrict__ ln2_s, const float* __restrict__ ln2_b,
    const float* __restrict__ b1, const float* __restrict__ b2,
    const float* __restrict__ gm, float* __restrict__ out)
{
    __shared__ __align__(16) char smem[EPI_LDS];
    f16* eol    = (f16*)(smem + OFF_EOL);
    float* etv  = (float*)(smem + OFF_ETV);
    f16* eh2    = (f16*)(smem + OFF_EH2);
    float* erd  = (float*)(smem + OFF_ERD);
    f16* ehid   = eol;

    const int tid = threadIdx.x;
    const int lane = tid & 63, wv = tid >> 6;
    const int lr = lane & 15, lg = lane >> 4;
    const int mb = wv * 16;
    const size_t tok0 = (size_t)blockIdx.x * 64;

    {
        const int tk = tid >> 2, part = tid & 3;
        const f16x8* src = (const f16x8*)(o_in + (tok0 + tk) * 128 + part * 32);
        f16x8* dst = (f16x8*)(eol + tk * EOLS + part * 32);
        dst[0] = src[0]; dst[1] = src[1]; dst[2] = src[2]; dst[3] = src[3];
    }
    __syncthreads();

    {   // upd = o @ Wo (K=128), fragment-layout weights
        f16x8 a_[4];
        #pragma unroll
        for (int ks = 0; ks < 4; ++ks)
            a_[ks] = *(const f16x8*)(eol + (mb + lr) * EOLS + ks*32 + lg*8);
        #pragma unroll
        for (int nt = 0; nt < 4; ++nt) {
            const int ch = nt * 16 + lr;
            f32x4 c = {0.f,0.f,0.f,0.f};
            #pragma unroll
            for (int ks = 0; ks < 4; ++ks)
                c = __builtin_amdgcn_mfma_f32_16x16x32_f16(a_[ks], *wfrag(FR_WO, 4, nt, ks, lg, lr), c, 0, 0, 0);
            const float bo_c = bo[ch], ga_c = gamma[ch];
            #pragma unroll
            for (int e = 0; e < 4; ++e) {
                const int tk = mb + lg*4 + e;
                etv[tk * ETVS + ch] = x[(tok0 + tk)*64 + ch] + ga_c * (c[e] + bo_c);
            }
        }
    }
    __syncthreads();

    {
        const int tk = tid >> 2, q = tid & 3;
        const float* tr = etv + tk * ETVS + q * 16;
        float s1 = 0.f, s2 = 0.f;
        #pragma unroll
        for (int j = 0; j < 16; ++j) { const float v = tr[j]; s1 += v; s2 += v*v; }
        erd[(tk*4 + q)*2] = s1; erd[(tk*4 + q)*2 + 1] = s2;
    }
    __syncthreads();
    {
        const int tk = tid >> 2, q = tid & 3;
        float a1 = 0.f, a2 = 0.f;
        #pragma unroll
        for (int i = 0; i < 4; ++i) { a1 += erd[(tk*4 + i)*2]; a2 += erd[(tk*4 + i)*2 + 1]; }
        const float mean = a1 * 0.015625f;
        const float rstd = rsqrtf(a2 * 0.015625f - mean*mean + 1e-5f);
        const float* tr = etv + tk * ETVS + q * 16;
        f16* hr = eh2 + tk * EH2S + q * 16;
        #pragma unroll
        for (int j = 0; j < 16; ++j)
            hr[j] = (f16)((tr[j]-mean)*rstd*ln2_s[q*16 + j] + ln2_b[q*16 + j]);
    }
    __syncthreads();

    {   // hid = gelu(h2 @ W1) (K=64)
        f16x8 a_[2];
        #pragma unroll
        for (int ks = 0; ks < 2; ++ks)
            a_[ks] = *(const f16x8*)(eh2 + (mb + lr) * EH2S + ks*32 + lg*8);
        #pragma unroll
        for (int nt = 0; nt < 8; ++nt) {
            const int ch = nt * 16 + lr;
            f32x4 c = {0.f,0.f,0.f,0.f};
            #pragma unroll
            for (int ks = 0; ks < 2; ++ks)
                c = __builtin_amdgcn_mfma_f32_16x16x32_f16(a_[ks], *wfrag(FR_W1, 2, nt, ks, lg, lr), c, 0, 0, 0);
            const float b1_c = b1[ch];
            #pragma unroll
            for (int e = 0; e < 4; ++e) {
                const int tk = mb + lg*4 + e;
                const float z = c[e] + b1_c;
                const float u = 0.7978845608028654f * (z + 0.044715f * z*z*z);
                ehid[tk * EOLS + ch] = (f16)(z / (1.0f + exp2fast(-2.8853900817779268f * u)));
            }
        }
    }
    __syncthreads();

    {   // oa = hid @ W2 (K=128); final residual
        f16x8 a_[4];
        #pragma unroll
        for (int ks = 0; ks < 4; ++ks)
            a_[ks] = *(const f16x8*)(ehid + (mb + lr) * EOLS + ks*32 + lg*8);
        #pragma unroll
        for (int nt = 0; nt < 4; ++nt) {
            const int ch = nt * 16 + lr;
            f32x4 c = {0.f,0.f,0.f,0.f};
            #pragma unroll
            for (int ks = 0; ks < 4; ++ks)
                c = __builtin_amdgcn_mfma_f32_16x16x32_f16(a_[ks], *wfrag(FR_W2, 4, nt, ks, lg, lr), c, 0, 0, 0);
            const float b2_c = b2[ch], gm_c = gm[ch];
            #pragma unroll
            for (int e = 0; e < 4; ++e) {
                const int tk = mb + lg*4 + e;
                out[(tok0 + tk)*64 + ch] = etv[tk * ETVS + ch] + gm_c * (c[e] + b2_c);
            }
        }
    }
}

extern "C" void kernel_launch(void* const* d_in, const int* in_sizes, int n_in,
                              void* d_out, int out_size, void* d_ws, size_t ws_size,
                              hipStream_t stream) {
    const float* x        = (const float*)d_in[0];
    const float* ln1_s    = (const float*)d_in[1];
    const float* ln1_b    = (const float*)d_in[2];
    const float* Wq       = (const float*)d_in[3];
    const float* Wkv      = (const float*)d_in[4];
    const float* bkv      = (const float*)d_in[5];
    const float* Wo       = (const float*)d_in[6];
    const float* bo       = (const float*)d_in[7];
    const float* gamma    = (const float*)d_in[8];
    const float* ln2_s    = (const float*)d_in[9];
    const float* ln2_b    = (const float*)d_in[10];
    const float* W1       = (const float*)d_in[11];
    const float* b1       = (const float*)d_in[12];
    const float* W2       = (const float*)d_in[13];
    const float* b2       = (const float*)d_in[14];
    const float* gamma_mlp= (const float*)d_in[15];

    // o (f16[65536][128]) aliases d_out (f32[65536][64]); disjoint token partition
    // between k_att writes and k_epi reads/overwrites -> race-free.
    f16* o_buf = (f16*)d_out;
    float* out = (float*)d_out;

    hipLaunchKernelGGL(k_conv, dim3(NWF / 256), dim3(256), 0, stream,
                       Wq, Wkv, Wo, W1, W2);
    hipLaunchKernelGGL(k_ln, dim3(1024), dim3(256), 0, stream,
                       x, ln1_s, ln1_b);
    hipLaunchKernelGGL(k_att, dim3(2048), dim3(256), 0, stream,
                       bkv, o_buf);
    hipLaunchKernelGGL(k_epi, dim3(1024), dim3(256), 0, stream,
                       x, o_buf, bo, gamma, ln2_s, ln2_b, b1, b2, gamma_mlp, out);
}

// Round 25
// 55.965 us; speedup vs baseline: 1.6026x; 1.0625x over previous
//
#include <hip/hip_runtime.h>
#include <math.h>

typedef _Float16 f16;
typedef _Float16 f16x2 __attribute__((ext_vector_type(2)));
typedef _Float16 f16x4 __attribute__((ext_vector_type(4)));
typedef _Float16 f16x8 __attribute__((ext_vector_type(8)));
typedef float f32x4 __attribute__((ext_vector_type(4)));

#if defined(__has_builtin)
#if __has_builtin(__builtin_amdgcn_fdot2)
#define USE_FDOT2 1
#endif
#if __has_builtin(__builtin_amdgcn_exp2f)
#define USE_EXP2 1
#endif
#if __has_builtin(__builtin_amdgcn_cvt_pkrtz)
#define USE_PKRTZ 1
#endif
#endif

__device__ __forceinline__ float fdot2f(f16x2 a, f16x2 b, float c) {
#ifdef USE_FDOT2
    return __builtin_amdgcn_fdot2(a, b, c, false);
#else
    return c + (float)a.x * (float)b.x + (float)a.y * (float)b.y;
#endif
}
__device__ __forceinline__ float exp2fast(float a) {
#ifdef USE_EXP2
    return __builtin_amdgcn_exp2f(a);
#else
    return exp2f(a);
#endif
}
__device__ __forceinline__ f16x2 pk2(float a, float b) {
#ifdef USE_PKRTZ
    auto r0 = __builtin_amdgcn_cvt_pkrtz(a, b);
    f16x2 r; __builtin_memcpy(&r, &r0, 4); return r;
#else
    return (f16x2){(f16)a, (f16)b};
#endif
}
__device__ __forceinline__ int f16x2_as_int(f16x2 v) { int r; __builtin_memcpy(&r, &v, 4); return r; }
__device__ __forceinline__ f16x2 int_as_f16x2(int v) { f16x2 r; __builtin_memcpy(&r, &v, 4); return r; }

namespace {
// ---- k_att constants (r25: ql removed -> 28160B LDS -> 5 blocks/CU) ----
constexpr int KS  = 40;
constexpr int VTS = 200;
constexpr int OFF_KL = 0;            // 192*40*2 = 15360
constexpr int OFF_VT = 15360;        // 12800 -> 28160
constexpr int ATT_LDS = 28160;       // x5 = 140800 <= 160K -> 5 blocks/CU
constexpr float C1  = 0.2550600f;
constexpr float CZN = -5.7707801f;
constexpr float CZV = 2.5511480f;

// ---- weights in MFMA B-FRAGMENT layout [ot][ks][lg][lr][j] f16 ----
constexpr int FR_WQ  = 0;        // IN=64  OUT=128 -> 8192
constexpr int FR_WKV = 8192;     // IN=64  OUT=256 -> 16384
constexpr int FR_WO  = 24576;    // IN=128 OUT=64  -> 8192
constexpr int FR_W1  = 32768;    // IN=64  OUT=128 -> 8192
constexpr int FR_W2  = 40960;    // IN=128 OUT=64  -> 8192
constexpr int NWF    = 49152;    // total f16 (96 KB)
constexpr int CONV_BLOCKS = NWF / 256;   // 192

// ---- k_epi constants (unchanged) ----
constexpr int EOLS = 136;
constexpr int ETVS = 66;
constexpr int EH2S = 72;
constexpr int OFF_EOL = 0;
constexpr int OFF_ETV = 17408;
constexpr int OFF_EH2 = 34304;
constexpr int OFF_ERD = 43520;
constexpr int EPI_LDS = 45568;
}

__device__ f16 g_wfrag[NWF];
// g_h in MFMA A-FRAGMENT layout: [tokblk(4096)][ks(2)][lg(4)][lr(16)][j(8)] f16.
__device__ f16 g_h[65536 * 64];

__device__ __forceinline__ const f16x8* hfrag(size_t tokblk, int ks, int lg, int lr) {
    return (const f16x8*)(g_h + (((tokblk * 2 + ks) * 4 + lg) * 16 + lr) * 8);
}
__device__ __forceinline__ const f16x8* wfrag(int base, int nks, int ot, int ks, int lg, int lr) {
    return (const f16x8*)(g_wfrag + base + (((ot * nks + ks) * 4 + lg) * 16 + lr) * 8);
}

// ---------------- Kernel 0 (merged): weight repack + LN1 -> g_h ----------------
__global__ __launch_bounds__(256, 8) void k_convln(
    const float* __restrict__ Wq, const float* __restrict__ Wkv,
    const float* __restrict__ Wo, const float* __restrict__ W1,
    const float* __restrict__ W2,
    const float* __restrict__ x,
    const float* __restrict__ ln1_s, const float* __restrict__ ln1_b) {
    const int bid = blockIdx.x;
    if (bid < CONV_BLOCKS) {
        const int i = bid * 256 + threadIdx.x;      // f16 element index
        const float* src; int IN, OUT, base;
        if (i < FR_WKV)      { src = Wq;  IN = 64;  OUT = 128; base = FR_WQ;  }
        else if (i < FR_WO)  { src = Wkv; IN = 64;  OUT = 256; base = FR_WKV; }
        else if (i < FR_W1)  { src = Wo;  IN = 128; OUT = 64;  base = FR_WO;  }
        else if (i < FR_W2)  { src = W1;  IN = 64;  OUT = 128; base = FR_W1;  }
        else                 { src = W2;  IN = 128; OUT = 64;  base = FR_W2;  }
        const int local = i - base;
        const int j  = local & 7;
        const int lr = (local >> 3) & 15;
        const int lg = (local >> 7) & 3;
        const int nks = IN >> 5;
        const int ks = (local >> 9) & (nks - 1);
        const int ot = local >> (9 + ((nks == 2) ? 1 : 2));
        const int in  = ks * 32 + lg * 8 + j;
        const int out = ot * 16 + lr;
        g_wfrag[i] = (f16)src[in * OUT + out];
        return;
    }
    // LN1 part: 1024 blocks of 64 tokens, 4 threads/token
    const int lb = bid - CONV_BLOCKS;
    const int tid = threadIdx.x;
    const size_t tok = (size_t)lb * 64 + (tid >> 2);
    const int q = tid & 3;
    const float* xr = x + tok * 64 + q * 16;
    float v[16];
    {
        const float4 a = ((const float4*)xr)[0], b = ((const float4*)xr)[1];
        const float4 c = ((const float4*)xr)[2], d = ((const float4*)xr)[3];
        v[0]=a.x; v[1]=a.y; v[2]=a.z; v[3]=a.w;  v[4]=b.x; v[5]=b.y; v[6]=b.z; v[7]=b.w;
        v[8]=c.x; v[9]=c.y; v[10]=c.z; v[11]=c.w; v[12]=d.x; v[13]=d.y; v[14]=d.z; v[15]=d.w;
    }
    float s = 0.f, ss = 0.f;
    #pragma unroll
    for (int j = 0; j < 16; ++j) { s += v[j]; ss += v[j]*v[j]; }
    s  += __shfl_xor(s, 1);  s  += __shfl_xor(s, 2);
    ss += __shfl_xor(ss, 1); ss += __shfl_xor(ss, 2);
    const float mean = s * 0.015625f;
    const float rstd = rsqrtf(ss * 0.015625f - mean*mean + 1e-5f);
    f16x8 p0, p1;
    #pragma unroll
    for (int j = 0; j < 8; ++j) {
        p0[j] = (f16)((v[j]     - mean) * rstd * ln1_s[q*16 + j]     + ln1_b[q*16 + j]);
        p1[j] = (f16)((v[j + 8] - mean) * rstd * ln1_s[q*16 + j + 8] + ln1_b[q*16 + j + 8]);
    }
    const size_t tokblk = tok >> 4;
    const int lr = (int)(tok & 15);
    const int ks = q >> 1, lg0 = (q & 1) * 2;
    *(f16x8*)(g_h + (((tokblk * 2 + ks) * 4 + lg0) * 16 + lr) * 8)     = p0;
    *(f16x8*)(g_h + (((tokblk * 2 + ks) * 4 + lg0 + 1) * 16 + lr) * 8) = p1;
}

// ---------------- Kernel 1: per-(window,head) attention; P AND Q in registers ----------
// r25: ql LDS removed. Wave wv's Q tiles are its own flash rows mA..mA+31, so the
// C-layout -> B-frag conversion is a wave-local shuffle transpose (same method as P).
__global__ __launch_bounds__(256, 5) void k_att(
    const float* __restrict__ bkv,
    f16* __restrict__ o_out)
{
    __shared__ __align__(16) char smem[ATT_LDS];
    f16* kl   = (f16*)(smem + OFF_KL);
    f16* vt   = (f16*)(smem + OFF_VT);

    const int tid  = threadIdx.x;
    const int bid  = blockIdx.x;
    const int w    = bid & 511;
    const int head = bid >> 9;
    const int cb   = head * 32;
    const int n    = w & 255;
    const int t    = w >> 8;

    const int lane = tid & 63, wv = tid >> 6;
    const int lr = lane & 15, lg = lane >> 4;
    const int mA = wv * 32;

    // Phase C: K/V projections -> LDS; Q projection -> registers (B-frag via shuffle)
    f16x8 bq0, bq1;
    {
        #pragma unroll
        for (int mi = 0; mi < 3; ++mi) {
            const int seg = wv * 3 + mi;                    // 0..11
            const int v_ = seg / 6;
            const int t2 = (seg % 6) + ((t == 0) ? 2 : 0);
            int tsrc, tt;
            if (t2 < 2)      { tsrc = t - 1; tt = t2 + 2; }
            else if (t2 < 6) { tsrc = t;     tt = t2 - 2; }
            else             { tsrc = t + 1; tt = t2 - 6; }
            const size_t tokblk = (size_t)(v_ * 8 + tsrc * 4 + tt) * 256 + n;
            const int mb = seg * 16;
            #pragma unroll
            for (int nt = 0; nt < 2; ++nt) {
                f32x4 ck = {0.f,0.f,0.f,0.f}, cv = {0.f,0.f,0.f,0.f};
                #pragma unroll
                for (int ks = 0; ks < 2; ++ks) {
                    const f16x8 af = *hfrag(tokblk, ks, lg, lr);
                    const f16x8 bk = *wfrag(FR_WKV, 2, head*2 + nt, ks, lg, lr);
                    const f16x8 bv = *wfrag(FR_WKV, 2, 8 + head*2 + nt, ks, lg, lr);
                    ck = __builtin_amdgcn_mfma_f32_16x16x32_f16(af, bk, ck, 0, 0, 0);
                    cv = __builtin_amdgcn_mfma_f32_16x16x32_f16(af, bv, cv, 0, 0, 0);
                }
                const float bk_b = bkv[cb + nt*16 + lr];
                const float bv_b = bkv[128 + cb + nt*16 + lr];
                #pragma unroll
                for (int e = 0; e < 4; ++e) {
                    const int row = mb + lg*4 + e;
                    kl[row * KS + nt*16 + lr] = (f16)(ck[e] + bk_b);
                    vt[(nt*16 + lr) * VTS + row] = (f16)(cv[e] + bv_b);
                }
            }
        }
        // Q: tiles qm=wv*2+mi are rows mA+mi*16 .. +16. Compute C-layout in regs,
        // then wave-local transpose to B-frag: value Q[row=mA+mi*16+lr][k=lg*8+j]
        // lives at source lane sl=(lr>>2)*16 + (lg&1)*8 + j, element e=lr&3, tile nt=lg>>1.
        #pragma unroll
        for (int mi = 0; mi < 2; ++mi) {
            const int qm = wv * 2 + mi;
            const int v_ = qm >> 2, tt = qm & 3;
            const size_t tokblk = (size_t)(v_ * 8 + t * 4 + tt) * 256 + n;
            int pkA[2], pkB[2];
            #pragma unroll
            for (int nt = 0; nt < 2; ++nt) {
                f32x4 cq = {0.f,0.f,0.f,0.f};
                #pragma unroll
                for (int ks = 0; ks < 2; ++ks) {
                    const f16x8 af = *hfrag(tokblk, ks, lg, lr);
                    const f16x8 bq = *wfrag(FR_WQ, 2, head*2 + nt, ks, lg, lr);
                    cq = __builtin_amdgcn_mfma_f32_16x16x32_f16(af, bq, cq, 0, 0, 0);
                }
                pkA[nt] = f16x2_as_int(pk2(cq[0], cq[1]));
                pkB[nt] = f16x2_as_int(pk2(cq[2], cq[3]));
            }
            f16x8 bq_;
            #pragma unroll
            for (int j = 0; j < 8; ++j) {
                const int sl = (lr >> 2) * 16 + (lg & 1) * 8 + j;
                const int a0 = __shfl(pkA[0], sl), b0 = __shfl(pkB[0], sl);
                const int a1 = __shfl(pkA[1], sl), b1 = __shfl(pkB[1], sl);
                const int s0 = (lr & 2) ? b0 : a0;
                const int s1 = (lr & 2) ? b1 : a1;
                const f16x2 vv = int_as_f16x2((lg >= 2) ? s1 : s0);
                bq_[j] = (lr & 1) ? vv.y : vv.x;
            }
            if (mi == 0) bq0 = bq_; else bq1 = bq_;
        }
    }

    // pz from register q (B-frag layout): lane holds row lr (bq0) / 16+lr (bq1),
    // channels lg*8+j; reduce over lg lanes.
    float pz0, pz1;
    {
        float s0 = 0.f, s1 = 0.f;
        #pragma unroll
        for (int j = 0; j < 8; ++j) {
            const float wgt = bkv[cb + lg*8 + j];
            s0 += (float)bq0[j] * wgt;
            s1 += (float)bq1[j] * wgt;
        }
        s0 += __shfl_xor(s0, 16); s0 += __shfl_xor(s0, 32);
        s1 += __shfl_xor(s1, 16); s1 += __shfl_xor(s1, 32);
        pz0 = exp2fast(fmaf(s0, C1, CZV));
        pz1 = exp2fast(fmaf(s1, C1, CZV));
    }

    __syncthreads();   // kl/vt ready (the kernel's only barrier)

    f32x4 oc00 = {0.f,0.f,0.f,0.f}, oc01 = {0.f,0.f,0.f,0.f};
    f32x4 oc10 = {0.f,0.f,0.f,0.f}, oc11 = {0.f,0.f,0.f,0.f};
    float l0 = 0.f, l1 = 0.f;

    #pragma unroll 1
    for (int kk = 0; kk < 6; ++kk) {
        const f16x8 ak0 = *(const f16x8*)(kl + (kk*32 + lr) * KS + lg * 8);
        const f16x8 ak1 = *(const f16x8*)(kl + (kk*32 + 16 + lr) * KS + lg * 8);
        const f32x4 ct00 = __builtin_amdgcn_mfma_f32_16x16x32_f16(ak0, bq0, (f32x4){0.f,0.f,0.f,0.f}, 0, 0, 0);
        const f32x4 ct01 = __builtin_amdgcn_mfma_f32_16x16x32_f16(ak0, bq1, (f32x4){0.f,0.f,0.f,0.f}, 0, 0, 0);
        const f32x4 ct10 = __builtin_amdgcn_mfma_f32_16x16x32_f16(ak1, bq0, (f32x4){0.f,0.f,0.f,0.f}, 0, 0, 0);
        const f32x4 ct11 = __builtin_amdgcn_mfma_f32_16x16x32_f16(ak1, bq1, (f32x4){0.f,0.f,0.f,0.f}, 0, 0, 0);

        float p00[4], p01[4], p10[4], p11[4];
        #pragma unroll
        for (int e = 0; e < 4; ++e) {
            p00[e] = exp2fast(fmaf(ct00[e], C1, CZN));
            p01[e] = exp2fast(fmaf(ct01[e], C1, CZN));
            p10[e] = exp2fast(fmaf(ct10[e], C1, CZN));
            p11[e] = exp2fast(fmaf(ct11[e], C1, CZN));
        }
        #pragma unroll
        for (int e = 0; e < 4; ++e) { l0 += p00[e] + p10[e]; l1 += p01[e] + p11[e]; }

        int pk0[4], pk1[4];
        #pragma unroll
        for (int e = 0; e < 4; ++e) {
            pk0[e] = f16x2_as_int(pk2(p00[e], p10[e]));
            pk1[e] = f16x2_as_int(pk2(p01[e], p11[e]));
        }
        f16x8 bp0, bp1;
        #pragma unroll
        for (int j = 0; j < 8; ++j) {
            const int sl = ((lg & 1) * 2 + (j >> 2)) * 16 + lr;
            const f16x2 v0 = int_as_f16x2(__shfl(pk0[j & 3], sl));
            const f16x2 v1 = int_as_f16x2(__shfl(pk1[j & 3], sl));
            bp0[j] = (lg < 2) ? v0.x : v0.y;
            bp1[j] = (lg < 2) ? v1.x : v1.y;
        }

        const f16x8 av0 = *(const f16x8*)(vt + lr * VTS + kk*32 + lg*8);
        const f16x8 av1 = *(const f16x8*)(vt + (16 + lr) * VTS + kk*32 + lg*8);
        oc00 = __builtin_amdgcn_mfma_f32_16x16x32_f16(av0, bp0, oc00, 0, 0, 0);
        oc01 = __builtin_amdgcn_mfma_f32_16x16x32_f16(av0, bp1, oc01, 0, 0, 0);
        oc10 = __builtin_amdgcn_mfma_f32_16x16x32_f16(av1, bp0, oc10, 0, 0, 0);
        oc11 = __builtin_amdgcn_mfma_f32_16x16x32_f16(av1, bp1, oc11, 0, 0, 0);
    }

    l0 += __shfl_xor(l0, 16); l0 += __shfl_xor(l0, 32);
    l1 += __shfl_xor(l1, 16); l1 += __shfl_xor(l1, 32);

    const float inv0 = 1.0f / (l0 + pz0), pzn0 = pz0 * inv0;
    const float inv1 = 1.0f / (l1 + pz1), pzn1 = pz1 * inv1;

    #define EPI_TILE(CC, MT, QT, INVQ, PZQ) { \
        const int q = mA + (QT) * 16 + lr; \
        const int v2 = q >> 6, tt2 = (q >> 4) & 3, nn2 = (q >> 2) & 3, dd2 = q & 3; \
        const size_t tk = ((size_t)(v2 * 8 + t * 4 + tt2) * 1024 + n * 4 + nn2) * 4 + dd2; \
        _Pragma("unroll") \
        for (int e = 0; e < 4; ++e) { \
            const int ch = (MT) * 16 + lg * 4 + e; \
            const float oo = fmaf(PZQ, bkv[128 + cb + ch], CC[e] * (INVQ)); \
            o_out[tk * 128 + cb + ch] = (f16)oo; \
        } }
    EPI_TILE(oc00, 0, 0, inv0, pzn0)
    EPI_TILE(oc01, 0, 1, inv1, pzn1)
    EPI_TILE(oc10, 1, 0, inv0, pzn0)
    EPI_TILE(oc11, 1, 1, inv1, pzn1)
    #undef EPI_TILE
}

// ---------------- Kernel 2: MFMA epilogue, 64 tokens/block (unchanged) ----------------
__global__ __launch_bounds__(256, 3) void k_epi(
    const float* __restrict__ x, const f16* __restrict__ o_in,
    const float* __restrict__ bo, const float* __restrict__ gamma,
    const float* __restrict__ ln2_s, const float* __restrict__ ln2_b,
    const float* __restrict__ b1, const float* __restrict__ b2,
    const float* __restrict__ gm, float* __restrict__ out)
{
    __shared__ __align__(16) char smem[EPI_LDS];
    f16* eol    = (f16*)(smem + OFF_EOL);
    float* etv  = (float*)(smem + OFF_ETV);
    f16* eh2    = (f16*)(smem + OFF_EH2);
    float* erd  = (float*)(smem + OFF_ERD);
    f16* ehid   = eol;

    const int tid = threadIdx.x;
    const int lane = tid & 63, wv = tid >> 6;
    const int lr = lane & 15, lg = lane >> 4;
    const int mb = wv * 16;
    const size_t tok0 = (size_t)blockIdx.x * 64;

    {
        const int tk = tid >> 2, part = tid & 3;
        const f16x8* src = (const f16x8*)(o_in + (tok0 + tk) * 128 + part * 32);
        f16x8* dst = (f16x8*)(eol + tk * EOLS + part * 32);
        dst[0] = src[0]; dst[1] = src[1]; dst[2] = src[2]; dst[3] = src[3];
    }
    __syncthreads();

    {
        f16x8 a_[4];
        #pragma unroll
        for (int ks = 0; ks < 4; ++ks)
            a_[ks] = *(const f16x8*)(eol + (mb + lr) * EOLS + ks*32 + lg*8);
        #pragma unroll
        for (int nt = 0; nt < 4; ++nt) {
            const int ch = nt * 16 + lr;
            f32x4 c = {0.f,0.f,0.f,0.f};
            #pragma unroll
            for (int ks = 0; ks < 4; ++ks)
                c = __builtin_amdgcn_mfma_f32_16x16x32_f16(a_[ks], *wfrag(FR_WO, 4, nt, ks, lg, lr), c, 0, 0, 0);
            const float bo_c = bo[ch], ga_c = gamma[ch];
            #pragma unroll
            for (int e = 0; e < 4; ++e) {
                const int tk = mb + lg*4 + e;
                etv[tk * ETVS + ch] = x[(tok0 + tk)*64 + ch] + ga_c * (c[e] + bo_c);
            }
        }
    }
    __syncthreads();

    {
        const int tk = tid >> 2, q = tid & 3;
        const float* tr = etv + tk * ETVS + q * 16;
        float s1 = 0.f, s2 = 0.f;
        #pragma unroll
        for (int j = 0; j < 16; ++j) { const float v = tr[j]; s1 += v; s2 += v*v; }
        erd[(tk*4 + q)*2] = s1; erd[(tk*4 + q)*2 + 1] = s2;
    }
    __syncthreads();
    {
        const int tk = tid >> 2, q = tid & 3;
        float a1 = 0.f, a2 = 0.f;
        #pragma unroll
        for (int i = 0; i < 4; ++i) { a1 += erd[(tk*4 + i)*2]; a2 += erd[(tk*4 + i)*2 + 1]; }
        const float mean = a1 * 0.015625f;
        const float rstd = rsqrtf(a2 * 0.015625f - mean*mean + 1e-5f);
        const float* tr = etv + tk * ETVS + q * 16;
        f16* hr = eh2 + tk * EH2S + q * 16;
        #pragma unroll
        for (int j = 0; j < 16; ++j)
            hr[j] = (f16)((tr[j]-mean)*rstd*ln2_s[q*16 + j] + ln2_b[q*16 + j]);
    }
    __syncthreads();

    {
        f16x8 a_[2];
        #pragma unroll
        for (int ks = 0; ks < 2; ++ks)
            a_[ks] = *(const f16x8*)(eh2 + (mb + lr) * EH2S + ks*32 + lg*8);
        #pragma unroll
        for (int nt = 0; nt < 8; ++nt) {
            const int ch = nt * 16 + lr;
            f32x4 c = {0.f,0.f,0.f,0.f};
            #pragma unroll
            for (int ks = 0; ks < 2; ++ks)
                c = __builtin_amdgcn_mfma_f32_16x16x32_f16(a_[ks], *wfrag(FR_W1, 2, nt, ks, lg, lr), c, 0, 0, 0);
            const float b1_c = b1[ch];
            #pragma unroll
            for (int e = 0; e < 4; ++e) {
                const int tk = mb + lg*4 + e;
                const float z = c[e] + b1_c;
                const float u = 0.7978845608028654f * (z + 0.044715f * z*z*z);
                ehid[tk * EOLS + ch] = (f16)(z / (1.0f + exp2fast(-2.8853900817779268f * u)));
            }
        }
    }
    __syncthreads();

    {
        f16x8 a_[4];
        #pragma unroll
        for (int ks = 0; ks < 4; ++ks)
            a_[ks] = *(const f16x8*)(ehid + (mb + lr) * EOLS + ks*32 + lg*8);
        #pragma unroll
        for (int nt = 0; nt < 4; ++nt) {
            const int ch = nt * 16 + lr;
            f32x4 c = {0.f,0.f,0.f,0.f};
            #pragma unroll
            for (int ks = 0; ks < 4; ++ks)
                c = __builtin_amdgcn_mfma_f32_16x16x32_f16(a_[ks], *wfrag(FR_W2, 4, nt, ks, lg, lr), c, 0, 0, 0);
            const float b2_c = b2[ch], gm_c = gm[ch];
            #pragma unroll
            for (int e = 0; e < 4; ++e) {
                const int tk = mb + lg*4 + e;
                out[(tok0 + tk)*64 + ch] = etv[tk * ETVS + ch] + gm_c * (c[e] + b2_c);
            }
        }
    }
}

extern "C" void kernel_launch(void* const* d_in, const int* in_sizes, int n_in,
                              void* d_out, int out_size, void* d_ws, size_t ws_size,
                              hipStream_t stream) {
    const float* x        = (const float*)d_in[0];
    const float* ln1_s    = (const float*)d_in[1];
    const float* ln1_b    = (const float*)d_in[2];
    const float* Wq       = (const float*)d_in[3];
    const float* Wkv      = (const float*)d_in[4];
    const float* bkv      = (const float*)d_in[5];
    const float* Wo       = (const float*)d_in[6];
    const float* bo       = (const float*)d_in[7];
    const float* gamma    = (const float*)d_in[8];
    const float* ln2_s    = (const float*)d_in[9];
    const float* ln2_b    = (const float*)d_in[10];
    const float* W1       = (const float*)d_in[11];
    const float* b1       = (const float*)d_in[12];
    const float* W2       = (const float*)d_in[13];
    const float* b2       = (const float*)d_in[14];
    const float* gamma_mlp= (const float*)d_in[15];

    // o (f16[65536][128]) aliases d_out (f32[65536][64]); disjoint token partition
    // between k_att writes and k_epi reads/overwrites -> race-free.
    f16* o_buf = (f16*)d_out;
    float* out = (float*)d_out;

    hipLaunchKernelGGL(k_convln, dim3(CONV_BLOCKS + 1024), dim3(256), 0, stream,
                       Wq, Wkv, Wo, W1, W2, x, ln1_s, ln1_b);
    hipLaunchKernelGGL(k_att, dim3(2048), dim3(256), 0, stream,
                       bkv, o_buf);
    hipLaunchKernelGGL(k_epi, dim3(1024), dim3(256), 0, stream,
                       x, o_buf, bo, gamma, ln2_s, ln2_b, b1, b2, gamma_mlp, out);
}